// Round 7
// baseline (712.909 us; speedup 1.0000x reference)
//
#include <hip/hip_runtime.h>

// ---------------------------------------------------------------------------
// MultiHeadSelfAttention: B=4, L=2048, D=1024, H=16, dh=64.
// R15: attn occupancy doubled the minimal-delta way. R13's attn inner code
// (4 q-tiles/wave, proven) kept byte-identical; block shrunk 4 waves -> 2
// waves (128 threads), grid 512 -> 1024, __launch_bounds__(128,4).
// 8 blocks/CU (147KB LDS/CU), 4 waves/SIMD = 2x R13 TLP.
// R14's restructured-inner variant (NaN, cause not isolated) discarded.
// Added sched_barrier(0) after the lgkmcnt wait (rule-#18 hazard class).
// GEMM/cvt unchanged from R13.
// ---------------------------------------------------------------------------

typedef __attribute__((ext_vector_type(8))) short short8;   // 8 bf16 = 4 VGPR
typedef __attribute__((ext_vector_type(4))) float f32x4;
typedef __attribute__((ext_vector_type(4))) float floatx4;
typedef __attribute__((ext_vector_type(4))) int int4v;
typedef __attribute__((ext_vector_type(2))) unsigned int u32x2;

#define MFMA16(a, b, c) __builtin_amdgcn_mfma_f32_16x16x32_bf16((a), (b), (c), 0, 0, 0)

__device__ __forceinline__ short f2bf(float f) {
    unsigned u = __float_as_uint(f);
    u += 0x7FFF + ((u >> 16) & 1);   // round-to-nearest-even
    return (short)(u >> 16);
}

__device__ __forceinline__ float fast_exp2(float x) {
#if __has_builtin(__builtin_amdgcn_exp2f)
    return __builtin_amdgcn_exp2f(x);   // single v_exp_f32
#else
    return exp2f(x);
#endif
}

// async global -> LDS, 16 B per lane (global_load_lds_dwordx4).
__device__ __forceinline__ void gload_lds16(const short* g, short* l) {
    __builtin_amdgcn_global_load_lds(
        (const __attribute__((address_space(1))) void*)g,
        (__attribute__((address_space(3))) void*)l, 16, 0, 0);
}

// ---------------------------------------------------------------------------
// fp32 -> bf16 bulk converts.
// ---------------------------------------------------------------------------
__device__ __forceinline__ void cvt8(const float* __restrict__ src,
                                     short* __restrict__ dst, int i) {
    const f32x4* p = (const f32x4*)src + (size_t)i * 2;
    const f32x4 u0 = p[0];
    const f32x4 u1 = p[1];
    short8 s;
    s[0] = f2bf(u0[0]); s[1] = f2bf(u0[1]); s[2] = f2bf(u0[2]); s[3] = f2bf(u0[3]);
    s[4] = f2bf(u1[0]); s[5] = f2bf(u1[1]); s[6] = f2bf(u1[2]); s[7] = f2bf(u1[3]);
    ((short8*)dst)[i] = s;
}

__global__ __launch_bounds__(256) void cvt_kernel(
    const float* __restrict__ src, short* __restrict__ dst, int n8)
{
    const int i = blockIdx.x * 256 + threadIdx.x;
    if (i >= n8) return;
    cvt8(src, dst, i);
}

__global__ __launch_bounds__(256) void cvt3_kernel(
    const float* __restrict__ s0, const float* __restrict__ s1,
    const float* __restrict__ s2, short* __restrict__ d0,
    short* __restrict__ d1, short* __restrict__ d2)
{
    const int which = blockIdx.x >> 9;
    const int i = (blockIdx.x & 511) * 256 + threadIdx.x;
    const float* s = which == 0 ? s0 : which == 1 ? s1 : s2;
    short* d = which == 0 ? d0 : which == 1 ? d1 : d2;
    cvt8(s, d, i);
}

__global__ __launch_bounds__(256) void cvt2_kernel(
    const float* __restrict__ s0, short* __restrict__ d0,
    const float* __restrict__ s1, short* __restrict__ d1)
{
    if (blockIdx.x < 4096) {
        cvt8(s0, d0, blockIdx.x * 256 + threadIdx.x);
    } else {
        cvt8(s1, d1, (blockIdx.x - 4096) * 256 + threadIdx.x);
    }
}

// ---------------------------------------------------------------------------
// GEMM body (m97 structure): out = A(8192 x 1024) * W^T + bias, bf16 in.
// 128x128 block tile, 4 waves each 64x64, BK=32. Staging via
// global_load_lds width 16 into linear LDS [128][32]. 2 barriers per K-step.
// layout 0/1 -> bf16 (B,H,L,dh); 2 -> bf16 (B,H,dh,L); 3 -> fp32 (M,1024).
// oscale multiplies (acc+bias) before store.
// ---------------------------------------------------------------------------
__device__ __forceinline__ void gemm_body(
    const short* __restrict__ A, const short* __restrict__ W,
    const float* __restrict__ bias, void* __restrict__ out,
    int layout, int m0, int n0, float oscale)
{
    __shared__ short As[128 * 32];
    __shared__ short Bs[128 * 32];

    const int t = threadIdx.x;
    const int wave = t >> 6, lane = t & 63;
    const int wm = (wave >> 1) * 64, wn = (wave & 1) * 64;
    const int l15 = lane & 15, quad = lane >> 4;

    const int r4 = lane >> 2;           // 0..15
    const int kc = (lane & 3) * 8;      // 0,8,16,24

    short* lA0 = &As[wave * 512 + lane * 8];
    short* lA1 = &As[2048 + wave * 512 + lane * 8];
    short* lB0 = &Bs[wave * 512 + lane * 8];
    short* lB1 = &Bs[2048 + wave * 512 + lane * 8];

    const short* gA0 = A + (size_t)(m0 + wave * 16 + r4) * 1024 + kc;
    const short* gA1 = gA0 + (size_t)64 * 1024;
    const short* gB0 = W + (size_t)(n0 + wave * 16 + r4) * 1024 + kc;
    const short* gB1 = gB0 + (size_t)64 * 1024;

    floatx4 acc[4][4];
#pragma unroll
    for (int i = 0; i < 4; i++)
#pragma unroll
        for (int j = 0; j < 4; j++) {
            acc[i][j][0] = 0.f; acc[i][j][1] = 0.f;
            acc[i][j][2] = 0.f; acc[i][j][3] = 0.f;
        }

    for (int kb = 0; kb < 1024; kb += 32) {
        gload_lds16(gA0 + kb, lA0);
        gload_lds16(gA1 + kb, lA1);
        gload_lds16(gB0 + kb, lB0);
        gload_lds16(gB1 + kb, lB1);
        __syncthreads();   // vmcnt(0) drain + barrier: LDS tile ready

        short8 af[4], bfr[4];
#pragma unroll
        for (int mi = 0; mi < 4; mi++)
            af[mi] = *(short8*)&As[(wm + mi * 16 + l15) * 32 + quad * 8];
#pragma unroll
        for (int ni = 0; ni < 4; ni++)
            bfr[ni] = *(short8*)&Bs[(wn + ni * 16 + l15) * 32 + quad * 8];
#pragma unroll
        for (int mi = 0; mi < 4; mi++)
#pragma unroll
            for (int ni = 0; ni < 4; ni++)
                acc[mi][ni] = MFMA16(af[mi], bfr[ni], acc[mi][ni]);

        __syncthreads();   // protect LDS from next K-step's staging
    }

    // Epilogue. C layout: col = lane&15, row = quad*4 + r.
#pragma unroll
    for (int ni = 0; ni < 4; ni++) {
        const int gn = n0 + wn + ni * 16 + l15;
        const float bv = bias[gn];
#pragma unroll
        for (int mi = 0; mi < 4; mi++) {
#pragma unroll
            for (int r = 0; r < 4; r++) {
                const int gm = m0 + wm + mi * 16 + quad * 4 + r;
                const float v = (acc[mi][ni][r] + bv) * oscale;
                if (layout == 3) {
                    ((float*)out)[(size_t)gm * 1024 + gn] = v;
                } else {
                    const int b = gm >> 11, l = gm & 2047;  // L = 2048
                    const int h = gn >> 6,  d = gn & 63;    // dh = 64
                    size_t idx;
                    if (layout == 2)
                        idx = ((size_t)(b * 16 + h) * 64 + d) * 2048 + l;
                    else
                        idx = ((size_t)(b * 16 + h) * 2048 + l) * 64 + d;
                    ((short*)out)[idx] = f2bf(v);
                }
            }
        }
    }
}

// fused QKV: grid (64, 24); blockIdx.y>>3 selects {Q,K,V} panel.
// Q panel is pre-scaled by SC = 0.125 * log2(e) (softmax scale folded in).
__global__ __launch_bounds__(256, 3) void qkv_kernel(
    const short* __restrict__ Xb,
    const short* __restrict__ Wq, const short* __restrict__ Wk,
    const short* __restrict__ Wv,
    const float* __restrict__ bq, const float* __restrict__ bk,
    const float* __restrict__ bv,
    short* __restrict__ Qo, short* __restrict__ Ko, short* __restrict__ Vo)
{
    const int chunk = blockIdx.y >> 3;            // 0=Q,1=K,2=V
    const int n0 = (blockIdx.y & 7) * 128;
    const short* W = chunk == 0 ? Wq : chunk == 1 ? Wk : Wv;
    const float* bs = chunk == 0 ? bq : chunk == 1 ? bk : bv;
    void* out = chunk == 0 ? (void*)Qo : chunk == 1 ? (void*)Ko : (void*)Vo;
    const float os = chunk == 0 ? 0.125f * 1.44269504f : 1.0f;
    gemm_body(Xb, W, bs, out, chunk, blockIdx.x * 128, n0, os);
}

__global__ __launch_bounds__(256, 3) void gemm_kernel(
    const short* __restrict__ A, const short* __restrict__ W,
    const float* __restrict__ bias, void* __restrict__ out, int layout)
{
    gemm_body(A, W, bias, out, layout, blockIdx.x * 128, blockIdx.y * 128, 1.0f);
}

// ---------------------------------------------------------------------------
// Attention. Q arrives pre-scaled by SC, so P = exp2(S + maskbias) directly.
// 1024 blocks x 2 waves (128 threads); each wave owns 4 q-tiles (64 rows) —
// inner code identical to the proven R13 kernel. Swapped QK^T (mfma(K,Q));
// P^T packed via v_cvt_pk_bf16_f32 -> ds_write_b64; mask as -1e9 accumulator
// seed; row sums via ones-column MFMA. XCD-affine: bh = blk & 63.
// Q,K bf16 (B,H,L,dh); VT bf16 (B,H,dh,L); mask int32; O fp32 (B,L,D).
// ---------------------------------------------------------------------------
__global__ __launch_bounds__(128, 4) void attn_kernel(
    const short* __restrict__ Q, const short* __restrict__ Kc,
    const short* __restrict__ VT, const int* __restrict__ mask,
    float* __restrict__ O)
{
    __shared__ short Plds_all[2][4][16 * 72];   // 18432 B

    const int blk = blockIdx.x;          // 1024 blocks
    const int bh = blk & 63;             // same bh -> same XCD
    const int qg = blk >> 6;             // 0..15 (128 rows each)
    const int b = bh >> 4, h = bh & 15;
    const int t = threadIdx.x;
    const int wave = t >> 6, lane = t & 63;   // wave 0..1
    const int l15 = lane & 15, quad = lane >> 4;

    const short* Qb = Q  + (size_t)bh * 2048 * 64;
    const short* Kb = Kc + (size_t)bh * 2048 * 64;
    const short* Vb = VT + (size_t)bh * 64 * 2048;
    const int* mrow = mask + b * 2048;

    const int qbase = qg * 128 + wave * 64;   // this wave: rows qbase..+63

    short8 aq[4][2];
#pragma unroll
    for (int tt = 0; tt < 4; tt++) {
        const short* qp = Qb + (size_t)(qbase + tt * 16 + l15) * 64 + quad * 8;
        aq[tt][0] = *(const short8*)(qp);
        aq[tt][1] = *(const short8*)(qp + 32);
    }

    short8 vone;
#pragma unroll
    for (int j = 0; j < 8; j++) vone[j] = (short)0x3F80;

    floatx4 accO[4][5];   // [tile][dh-block 0..3, 4 = row-sum]
#pragma unroll
    for (int tt = 0; tt < 4; tt++)
#pragma unroll
        for (int ni = 0; ni < 5; ni++) {
            accO[tt][ni][0] = 0.f; accO[tt][ni][1] = 0.f;
            accO[tt][ni][2] = 0.f; accO[tt][ni][3] = 0.f;
        }

    for (int c0 = 0; c0 < 2048; c0 += 64) {
        short8 kreg[4][2];
#pragma unroll
        for (int g = 0; g < 4; g++) {
            const short* kp = Kb + (size_t)(c0 + g * 16 + l15) * 64 + quad * 8;
            kreg[g][0] = *(const short8*)(kp);
            kreg[g][1] = *(const short8*)(kp + 32);
        }
        f32x4 bias[4];
#pragma unroll
        for (int g = 0; g < 4; g++) {
            const int4v mv = *(const int4v*)&mrow[c0 + g * 16 + quad * 4];
#pragma unroll
            for (int r = 0; r < 4; r++) bias[g][r] = mv[r] ? -1e9f : 0.f;
        }
        short8 vreg[4][2];
#pragma unroll
        for (int ni = 0; ni < 4; ni++) {
            const short* vp = Vb + (size_t)(ni * 16 + l15) * 2048 + c0 + quad * 8;
            vreg[ni][0] = *(const short8*)(vp);
            vreg[ni][1] = *(const short8*)(vp + 32);
        }

#pragma unroll
        for (int tt = 0; tt < 4; tt++) {
            floatx4 s[4];
            __builtin_amdgcn_s_setprio(1);
#pragma unroll
            for (int g = 0; g < 4; g++) {
                floatx4 z = bias[g];
                z = MFMA16(kreg[g][0], aq[tt][0], z);
                s[g] = MFMA16(kreg[g][1], aq[tt][1], z);
            }
            __builtin_amdgcn_s_setprio(0);
            short* Pl = &Plds_all[wave][tt][0];
#pragma unroll
            for (int g = 0; g < 4; g++) {
                const float p0 = fast_exp2(s[g][0]);
                const float p1 = fast_exp2(s[g][1]);
                const float p2 = fast_exp2(s[g][2]);
                const float p3 = fast_exp2(s[g][3]);
                unsigned lo, hi;
                asm("v_cvt_pk_bf16_f32 %0, %1, %2" : "=v"(lo) : "v"(p0), "v"(p1));
                asm("v_cvt_pk_bf16_f32 %0, %1, %2" : "=v"(hi) : "v"(p2), "v"(p3));
                u32x2 w; w[0] = lo; w[1] = hi;
                *(u32x2*)&Pl[l15 * 72 + g * 16 + quad * 4] = w;
            }
        }

        asm volatile("s_waitcnt lgkmcnt(0)" ::: "memory");
        __builtin_amdgcn_sched_barrier(0);

#pragma unroll
        for (int tt = 0; tt < 4; tt++) {
            const short* Pl = &Plds_all[wave][tt][0];
            const short8 pa0 = *(const short8*)&Pl[l15 * 72 + quad * 8];
            const short8 pa1 = *(const short8*)&Pl[l15 * 72 + 32 + quad * 8];
            __builtin_amdgcn_s_setprio(1);
#pragma unroll
            for (int ni = 0; ni < 4; ni++) {
                accO[tt][ni] = MFMA16(pa0, vreg[ni][0], accO[tt][ni]);
                accO[tt][ni] = MFMA16(pa1, vreg[ni][1], accO[tt][ni]);
            }
            accO[tt][4] = MFMA16(pa0, vone, accO[tt][4]);
            accO[tt][4] = MFMA16(pa1, vone, accO[tt][4]);
            __builtin_amdgcn_s_setprio(0);
        }
    }

#pragma unroll
    for (int tt = 0; tt < 4; tt++) {
#pragma unroll
        for (int r = 0; r < 4; r++) {
            const float inv = 1.0f / fmaxf(accO[tt][4][r], 1e-30f);
            const int l = qbase + tt * 16 + quad * 4 + r;
#pragma unroll
            for (int ni = 0; ni < 4; ni++) {
                O[(size_t)(b * 2048 + l) * 1024 + h * 64 + ni * 16 + l15] =
                    accO[tt][ni][r] * inv;
            }
        }
    }
}

// ---------------------------------------------------------------------------
extern "C" void kernel_launch(void* const* d_in, const int* in_sizes, int n_in,
                              void* d_out, int out_size, void* d_ws, size_t ws_size,
                              hipStream_t stream)
{
    const float* x    = (const float*)d_in[0];
    const int*   mask = (const int*)d_in[1];
    const float* wq   = (const float*)d_in[2];
    const float* bq   = (const float*)d_in[3];
    const float* wk   = (const float*)d_in[4];
    const float* bk   = (const float*)d_in[5];
    const float* wv   = (const float*)d_in[6];
    const float* bv   = (const float*)d_in[7];
    const float* wo   = (const float*)d_in[8];
    const float* bo   = (const float*)d_in[9];
    float* out = (float*)d_out;   // fp32 output (8M floats)

    // ws (48 MiB): [Qbuf bf16 16MB][Kbuf bf16 16MB][Vt bf16 16MB]
    short* Qbuf = (short*)d_ws;
    short* Kbuf = Qbuf + (size_t)8 * 1024 * 1024;
    short* Vt   = Kbuf + (size_t)8 * 1024 * 1024;

    // d_out doubles as scratch until attn writes it.
    short* Xb  = (short*)d_out;
    short* Wqb = Xb  + (size_t)8 * 1024 * 1024;
    short* Wkb = Wqb + (size_t)1024 * 1024;
    short* Wvb = Wkb + (size_t)1024 * 1024;

    dim3 block(256);

    cvt_kernel<<<dim3(4096), block, 0, stream>>>(x, Xb, 1024 * 1024);
    cvt3_kernel<<<dim3(1536), block, 0, stream>>>(wq, wk, wv, Wqb, Wkb, Wvb);

    qkv_kernel<<<dim3(64, 24), block, 0, stream>>>(
        Xb, Wqb, Wkb, Wvb, bq, bk, bv, Qbuf, Kbuf, Vt);

    attn_kernel<<<dim3(1024), dim3(128), 0, stream>>>(Qbuf, Kbuf, Vt, mask, out);

    short* Ob  = Qbuf;
    short* Wob = Kbuf;
    cvt2_kernel<<<dim3(4608), block, 0, stream>>>(out, Ob, wo, Wob);

    gemm_kernel<<<dim3(64, 8), block, 0, stream>>>(Ob, Wob, bo, out, 3);
}

// Round 8
// 495.042 us; speedup vs baseline: 1.4401x; 1.4401x over previous
//
#include <hip/hip_runtime.h>

// ---------------------------------------------------------------------------
// MultiHeadSelfAttention: B=4, L=2048, D=1024, H=16, dh=64.
// R16: attn reverted to the proven R13 geometry (512 blocks x 256 thr,
// __launch_bounds__(256,2), 4 q-tiles/wave) + K/mask register double-buffer:
// next tile's K fragments + mask bias prefetched during the current tile's
// compute (T14 issue-early), so QK never stalls on K latency. V stays
// single-buffered (hidden under QK/softmax). Named buffers ka/kb2 (rule #20).
// R14/R15 occupancy routes abandoned (NaN / 64-VGPR spill, 871MB scratch).
// GEMM/cvt unchanged from R13.
// ---------------------------------------------------------------------------

typedef __attribute__((ext_vector_type(8))) short short8;   // 8 bf16 = 4 VGPR
typedef __attribute__((ext_vector_type(4))) float f32x4;
typedef __attribute__((ext_vector_type(4))) float floatx4;
typedef __attribute__((ext_vector_type(4))) int int4v;
typedef __attribute__((ext_vector_type(2))) unsigned int u32x2;

#define MFMA16(a, b, c) __builtin_amdgcn_mfma_f32_16x16x32_bf16((a), (b), (c), 0, 0, 0)

__device__ __forceinline__ short f2bf(float f) {
    unsigned u = __float_as_uint(f);
    u += 0x7FFF + ((u >> 16) & 1);   // round-to-nearest-even
    return (short)(u >> 16);
}

__device__ __forceinline__ float fast_exp2(float x) {
#if __has_builtin(__builtin_amdgcn_exp2f)
    return __builtin_amdgcn_exp2f(x);   // single v_exp_f32
#else
    return exp2f(x);
#endif
}

// async global -> LDS, 16 B per lane (global_load_lds_dwordx4).
__device__ __forceinline__ void gload_lds16(const short* g, short* l) {
    __builtin_amdgcn_global_load_lds(
        (const __attribute__((address_space(1))) void*)g,
        (__attribute__((address_space(3))) void*)l, 16, 0, 0);
}

// ---------------------------------------------------------------------------
// fp32 -> bf16 bulk converts.
// ---------------------------------------------------------------------------
__device__ __forceinline__ void cvt8(const float* __restrict__ src,
                                     short* __restrict__ dst, int i) {
    const f32x4* p = (const f32x4*)src + (size_t)i * 2;
    const f32x4 u0 = p[0];
    const f32x4 u1 = p[1];
    short8 s;
    s[0] = f2bf(u0[0]); s[1] = f2bf(u0[1]); s[2] = f2bf(u0[2]); s[3] = f2bf(u0[3]);
    s[4] = f2bf(u1[0]); s[5] = f2bf(u1[1]); s[6] = f2bf(u1[2]); s[7] = f2bf(u1[3]);
    ((short8*)dst)[i] = s;
}

__global__ __launch_bounds__(256) void cvt_kernel(
    const float* __restrict__ src, short* __restrict__ dst, int n8)
{
    const int i = blockIdx.x * 256 + threadIdx.x;
    if (i >= n8) return;
    cvt8(src, dst, i);
}

__global__ __launch_bounds__(256) void cvt3_kernel(
    const float* __restrict__ s0, const float* __restrict__ s1,
    const float* __restrict__ s2, short* __restrict__ d0,
    short* __restrict__ d1, short* __restrict__ d2)
{
    const int which = blockIdx.x >> 9;
    const int i = (blockIdx.x & 511) * 256 + threadIdx.x;
    const float* s = which == 0 ? s0 : which == 1 ? s1 : s2;
    short* d = which == 0 ? d0 : which == 1 ? d1 : d2;
    cvt8(s, d, i);
}

__global__ __launch_bounds__(256) void cvt2_kernel(
    const float* __restrict__ s0, short* __restrict__ d0,
    const float* __restrict__ s1, short* __restrict__ d1)
{
    if (blockIdx.x < 4096) {
        cvt8(s0, d0, blockIdx.x * 256 + threadIdx.x);
    } else {
        cvt8(s1, d1, (blockIdx.x - 4096) * 256 + threadIdx.x);
    }
}

// ---------------------------------------------------------------------------
// GEMM body (m97 structure): out = A(8192 x 1024) * W^T + bias, bf16 in.
// 128x128 block tile, 4 waves each 64x64, BK=32. Staging via
// global_load_lds width 16 into linear LDS [128][32]. 2 barriers per K-step.
// layout 0/1 -> bf16 (B,H,L,dh); 2 -> bf16 (B,H,dh,L); 3 -> fp32 (M,1024).
// oscale multiplies (acc+bias) before store.
// ---------------------------------------------------------------------------
__device__ __forceinline__ void gemm_body(
    const short* __restrict__ A, const short* __restrict__ W,
    const float* __restrict__ bias, void* __restrict__ out,
    int layout, int m0, int n0, float oscale)
{
    __shared__ short As[128 * 32];
    __shared__ short Bs[128 * 32];

    const int t = threadIdx.x;
    const int wave = t >> 6, lane = t & 63;
    const int wm = (wave >> 1) * 64, wn = (wave & 1) * 64;
    const int l15 = lane & 15, quad = lane >> 4;

    const int r4 = lane >> 2;           // 0..15
    const int kc = (lane & 3) * 8;      // 0,8,16,24

    short* lA0 = &As[wave * 512 + lane * 8];
    short* lA1 = &As[2048 + wave * 512 + lane * 8];
    short* lB0 = &Bs[wave * 512 + lane * 8];
    short* lB1 = &Bs[2048 + wave * 512 + lane * 8];

    const short* gA0 = A + (size_t)(m0 + wave * 16 + r4) * 1024 + kc;
    const short* gA1 = gA0 + (size_t)64 * 1024;
    const short* gB0 = W + (size_t)(n0 + wave * 16 + r4) * 1024 + kc;
    const short* gB1 = gB0 + (size_t)64 * 1024;

    floatx4 acc[4][4];
#pragma unroll
    for (int i = 0; i < 4; i++)
#pragma unroll
        for (int j = 0; j < 4; j++) {
            acc[i][j][0] = 0.f; acc[i][j][1] = 0.f;
            acc[i][j][2] = 0.f; acc[i][j][3] = 0.f;
        }

    for (int kb = 0; kb < 1024; kb += 32) {
        gload_lds16(gA0 + kb, lA0);
        gload_lds16(gA1 + kb, lA1);
        gload_lds16(gB0 + kb, lB0);
        gload_lds16(gB1 + kb, lB1);
        __syncthreads();   // vmcnt(0) drain + barrier: LDS tile ready

        short8 af[4], bfr[4];
#pragma unroll
        for (int mi = 0; mi < 4; mi++)
            af[mi] = *(short8*)&As[(wm + mi * 16 + l15) * 32 + quad * 8];
#pragma unroll
        for (int ni = 0; ni < 4; ni++)
            bfr[ni] = *(short8*)&Bs[(wn + ni * 16 + l15) * 32 + quad * 8];
#pragma unroll
        for (int mi = 0; mi < 4; mi++)
#pragma unroll
            for (int ni = 0; ni < 4; ni++)
                acc[mi][ni] = MFMA16(af[mi], bfr[ni], acc[mi][ni]);

        __syncthreads();   // protect LDS from next K-step's staging
    }

    // Epilogue. C layout: col = lane&15, row = quad*4 + r.
#pragma unroll
    for (int ni = 0; ni < 4; ni++) {
        const int gn = n0 + wn + ni * 16 + l15;
        const float bv = bias[gn];
#pragma unroll
        for (int mi = 0; mi < 4; mi++) {
#pragma unroll
            for (int r = 0; r < 4; r++) {
                const int gm = m0 + wm + mi * 16 + quad * 4 + r;
                const float v = (acc[mi][ni][r] + bv) * oscale;
                if (layout == 3) {
                    ((float*)out)[(size_t)gm * 1024 + gn] = v;
                } else {
                    const int b = gm >> 11, l = gm & 2047;  // L = 2048
                    const int h = gn >> 6,  d = gn & 63;    // dh = 64
                    size_t idx;
                    if (layout == 2)
                        idx = ((size_t)(b * 16 + h) * 64 + d) * 2048 + l;
                    else
                        idx = ((size_t)(b * 16 + h) * 2048 + l) * 64 + d;
                    ((short*)out)[idx] = f2bf(v);
                }
            }
        }
    }
}

// fused QKV: grid (64, 24); blockIdx.y>>3 selects {Q,K,V} panel.
// Q panel is pre-scaled by SC = 0.125 * log2(e) (softmax scale folded in).
__global__ __launch_bounds__(256, 3) void qkv_kernel(
    const short* __restrict__ Xb,
    const short* __restrict__ Wq, const short* __restrict__ Wk,
    const short* __restrict__ Wv,
    const float* __restrict__ bq, const float* __restrict__ bk,
    const float* __restrict__ bv,
    short* __restrict__ Qo, short* __restrict__ Ko, short* __restrict__ Vo)
{
    const int chunk = blockIdx.y >> 3;            // 0=Q,1=K,2=V
    const int n0 = (blockIdx.y & 7) * 128;
    const short* W = chunk == 0 ? Wq : chunk == 1 ? Wk : Wv;
    const float* bs = chunk == 0 ? bq : chunk == 1 ? bk : bv;
    void* out = chunk == 0 ? (void*)Qo : chunk == 1 ? (void*)Ko : (void*)Vo;
    const float os = chunk == 0 ? 0.125f * 1.44269504f : 1.0f;
    gemm_body(Xb, W, bs, out, chunk, blockIdx.x * 128, n0, os);
}

__global__ __launch_bounds__(256, 3) void gemm_kernel(
    const short* __restrict__ A, const short* __restrict__ W,
    const float* __restrict__ bias, void* __restrict__ out, int layout)
{
    gemm_body(A, W, bias, out, layout, blockIdx.x * 128, blockIdx.y * 128, 1.0f);
}

// ---------------------------------------------------------------------------
// Attention. Q arrives pre-scaled by SC, so P = exp2(S + maskbias) directly.
// 512 blocks x 4 waves; each wave owns 4 q-tiles (64 rows). Swapped QK^T
// (mfma(K,Q)); P^T packed via v_cvt_pk_bf16_f32 -> ds_write_b64; mask as
// -1e9 accumulator seed; row sums via ones-column MFMA.
// K/mask register double-buffer: next tile's K + bias prefetched during the
// current tile's compute, so QK never waits on K latency. V single-buffered
// (hidden under QK/softmax). XCD-affine: bh = blk & 63.
// Q,K bf16 (B,H,L,dh); VT bf16 (B,H,dh,L); mask int32; O fp32 (B,L,D).
// ---------------------------------------------------------------------------
__global__ __launch_bounds__(256, 2) void attn_kernel(
    const short* __restrict__ Q, const short* __restrict__ Kc,
    const short* __restrict__ VT, const int* __restrict__ mask,
    float* __restrict__ O)
{
    __shared__ short Plds_all[4][4][16 * 72];   // 36864 B

    const int blk = blockIdx.x;          // 512 blocks
    const int bh = blk & 63;             // same bh -> same XCD
    const int qg = blk >> 6;             // 0..7 (256 rows each)
    const int b = bh >> 4, h = bh & 15;
    const int t = threadIdx.x;
    const int wave = t >> 6, lane = t & 63;
    const int l15 = lane & 15, quad = lane >> 4;

    const short* Qb = Q  + (size_t)bh * 2048 * 64;
    const short* Kb = Kc + (size_t)bh * 2048 * 64;
    const short* Vb = VT + (size_t)bh * 64 * 2048;
    const int* mrow = mask + b * 2048;

    const int qbase = qg * 256 + wave * 64;

    short8 aq[4][2];
#pragma unroll
    for (int tt = 0; tt < 4; tt++) {
        const short* qp = Qb + (size_t)(qbase + tt * 16 + l15) * 64 + quad * 8;
        aq[tt][0] = *(const short8*)(qp);
        aq[tt][1] = *(const short8*)(qp + 32);
    }

    short8 vone;
#pragma unroll
    for (int j = 0; j < 8; j++) vone[j] = (short)0x3F80;

    floatx4 accO[4][5];
#pragma unroll
    for (int tt = 0; tt < 4; tt++)
#pragma unroll
        for (int ni = 0; ni < 5; ni++) {
            accO[tt][ni][0] = 0.f; accO[tt][ni][1] = 0.f;
            accO[tt][ni][2] = 0.f; accO[tt][ni][3] = 0.f;
        }

    // K + mask-bias double buffers (named, static indexing only).
    short8 ka[4][2], kb2[4][2];
    f32x4 ba[4], bb[4];

#define LOADK(kr, br, c0) do {                                                \
    _Pragma("unroll")                                                         \
    for (int g = 0; g < 4; g++) {                                             \
        const short* kp = Kb + (size_t)((c0) + g * 16 + l15) * 64 + quad * 8; \
        kr[g][0] = *(const short8*)(kp);                                      \
        kr[g][1] = *(const short8*)(kp + 32);                                 \
    }                                                                         \
    _Pragma("unroll")                                                         \
    for (int g = 0; g < 4; g++) {                                             \
        const int4v mv = *(const int4v*)&mrow[(c0) + g * 16 + quad * 4];      \
        _Pragma("unroll")                                                     \
        for (int r = 0; r < 4; r++) (br)[g][r] = mv[r] ? -1e9f : 0.f;         \
    }                                                                         \
} while (0)

#define TILE(kr, br, c0, pf, knext, bnext, c0n) do {                          \
    short8 vreg[4][2];                                                        \
    _Pragma("unroll")                                                         \
    for (int ni = 0; ni < 4; ni++) {                                          \
        const short* vp = Vb + (size_t)(ni * 16 + l15) * 2048 + (c0) + quad * 8; \
        vreg[ni][0] = *(const short8*)(vp);                                   \
        vreg[ni][1] = *(const short8*)(vp + 32);                              \
    }                                                                         \
    if (pf) LOADK(knext, bnext, c0n);                                         \
    _Pragma("unroll")                                                         \
    for (int tt = 0; tt < 4; tt++) {                                          \
        floatx4 s[4];                                                         \
        __builtin_amdgcn_s_setprio(1);                                        \
        _Pragma("unroll")                                                     \
        for (int g = 0; g < 4; g++) {                                         \
            floatx4 z = br[g];                                                \
            z = MFMA16(kr[g][0], aq[tt][0], z);                               \
            s[g] = MFMA16(kr[g][1], aq[tt][1], z);                            \
        }                                                                     \
        __builtin_amdgcn_s_setprio(0);                                        \
        short* Pl = &Plds_all[wave][tt][0];                                   \
        _Pragma("unroll")                                                     \
        for (int g = 0; g < 4; g++) {                                         \
            const float p0 = fast_exp2(s[g][0]);                              \
            const float p1 = fast_exp2(s[g][1]);                              \
            const float p2 = fast_exp2(s[g][2]);                              \
            const float p3 = fast_exp2(s[g][3]);                              \
            unsigned lo, hi;                                                  \
            asm("v_cvt_pk_bf16_f32 %0, %1, %2" : "=v"(lo) : "v"(p0), "v"(p1));\
            asm("v_cvt_pk_bf16_f32 %0, %1, %2" : "=v"(hi) : "v"(p2), "v"(p3));\
            u32x2 w; w[0] = lo; w[1] = hi;                                    \
            *(u32x2*)&Pl[l15 * 72 + g * 16 + quad * 4] = w;                   \
        }                                                                     \
    }                                                                         \
    asm volatile("s_waitcnt lgkmcnt(0)" ::: "memory");                        \
    __builtin_amdgcn_sched_barrier(0);                                        \
    _Pragma("unroll")                                                         \
    for (int tt = 0; tt < 4; tt++) {                                          \
        const short* Pl = &Plds_all[wave][tt][0];                             \
        const short8 pa0 = *(const short8*)&Pl[l15 * 72 + quad * 8];          \
        const short8 pa1 = *(const short8*)&Pl[l15 * 72 + 32 + quad * 8];     \
        __builtin_amdgcn_s_setprio(1);                                        \
        _Pragma("unroll")                                                     \
        for (int ni = 0; ni < 4; ni++) {                                      \
            accO[tt][ni] = MFMA16(pa0, vreg[ni][0], accO[tt][ni]);            \
            accO[tt][ni] = MFMA16(pa1, vreg[ni][1], accO[tt][ni]);            \
        }                                                                     \
        accO[tt][4] = MFMA16(pa0, vone, accO[tt][4]);                         \
        accO[tt][4] = MFMA16(pa1, vone, accO[tt][4]);                         \
        __builtin_amdgcn_s_setprio(0);                                        \
    }                                                                         \
} while (0)

    LOADK(ka, ba, 0);
    for (int c0 = 0; c0 < 2048; c0 += 128) {
        TILE(ka, ba, c0, 1, kb2, bb, c0 + 64);
        TILE(kb2, bb, c0 + 64, (c0 + 128 < 2048), ka, ba, c0 + 128);
    }
#undef TILE
#undef LOADK

#pragma unroll
    for (int tt = 0; tt < 4; tt++) {
#pragma unroll
        for (int r = 0; r < 4; r++) {
            const float inv = 1.0f / fmaxf(accO[tt][4][r], 1e-30f);
            const int l = qbase + tt * 16 + quad * 4 + r;
#pragma unroll
            for (int ni = 0; ni < 4; ni++) {
                O[(size_t)(b * 2048 + l) * 1024 + h * 64 + ni * 16 + l15] =
                    accO[tt][ni][r] * inv;
            }
        }
    }
}

// ---------------------------------------------------------------------------
extern "C" void kernel_launch(void* const* d_in, const int* in_sizes, int n_in,
                              void* d_out, int out_size, void* d_ws, size_t ws_size,
                              hipStream_t stream)
{
    const float* x    = (const float*)d_in[0];
    const int*   mask = (const int*)d_in[1];
    const float* wq   = (const float*)d_in[2];
    const float* bq   = (const float*)d_in[3];
    const float* wk   = (const float*)d_in[4];
    const float* bk   = (const float*)d_in[5];
    const float* wv   = (const float*)d_in[6];
    const float* bv   = (const float*)d_in[7];
    const float* wo   = (const float*)d_in[8];
    const float* bo   = (const float*)d_in[9];
    float* out = (float*)d_out;   // fp32 output (8M floats)

    // ws (48 MiB): [Qbuf bf16 16MB][Kbuf bf16 16MB][Vt bf16 16MB]
    short* Qbuf = (short*)d_ws;
    short* Kbuf = Qbuf + (size_t)8 * 1024 * 1024;
    short* Vt   = Kbuf + (size_t)8 * 1024 * 1024;

    // d_out doubles as scratch until attn writes it.
    short* Xb  = (short*)d_out;
    short* Wqb = Xb  + (size_t)8 * 1024 * 1024;
    short* Wkb = Wqb + (size_t)1024 * 1024;
    short* Wvb = Wkb + (size_t)1024 * 1024;

    dim3 block(256);

    cvt_kernel<<<dim3(4096), block, 0, stream>>>(x, Xb, 1024 * 1024);
    cvt3_kernel<<<dim3(1536), block, 0, stream>>>(wq, wk, wv, Wqb, Wkb, Wvb);

    qkv_kernel<<<dim3(64, 24), block, 0, stream>>>(
        Xb, Wqb, Wkb, Wvb, bq, bk, bv, Qbuf, Kbuf, Vt);

    attn_kernel<<<dim3(512), block, 0, stream>>>(Qbuf, Kbuf, Vt, mask, out);

    short* Ob  = Qbuf;
    short* Wob = Kbuf;
    cvt2_kernel<<<dim3(4608), block, 0, stream>>>(out, Ob, wo, Wob);

    gemm_kernel<<<dim3(64, 8), block, 0, stream>>>(Ob, Wob, bo, out, 3);
}

// Round 10
// 361.894 us; speedup vs baseline: 1.9699x; 1.3679x over previous
//
#include <hip/hip_runtime.h>

// ---------------------------------------------------------------------------
// MultiHeadSelfAttention: B=4, L=2048, D=1024, H=16, dh=64.
// R17 (resubmit — prior round was an infra failure, kernel never ran).
// Consolidation: attn = exact R13 kernel (passed twice, 144us, VGPR 116 —
// every structural perturbation since regressed: R14 NaN, R15/R16 spills).
// GEMM phase = R13 (m97-structure, gload_lds16, fused QKV, Q pre-scaled).
// Only delta vs R13: cvt_x + cvt3_w merged into one cvt4 launch.
// ---------------------------------------------------------------------------

typedef __attribute__((ext_vector_type(8))) short short8;   // 8 bf16 = 4 VGPR
typedef __attribute__((ext_vector_type(4))) float f32x4;
typedef __attribute__((ext_vector_type(4))) float floatx4;
typedef __attribute__((ext_vector_type(4))) int int4v;
typedef __attribute__((ext_vector_type(2))) unsigned int u32x2;

#define MFMA16(a, b, c) __builtin_amdgcn_mfma_f32_16x16x32_bf16((a), (b), (c), 0, 0, 0)

__device__ __forceinline__ short f2bf(float f) {
    unsigned u = __float_as_uint(f);
    u += 0x7FFF + ((u >> 16) & 1);   // round-to-nearest-even
    return (short)(u >> 16);
}

__device__ __forceinline__ float fast_exp2(float x) {
#if __has_builtin(__builtin_amdgcn_exp2f)
    return __builtin_amdgcn_exp2f(x);   // single v_exp_f32
#else
    return exp2f(x);
#endif
}

// async global -> LDS, 16 B per lane (global_load_lds_dwordx4).
__device__ __forceinline__ void gload_lds16(const short* g, short* l) {
    __builtin_amdgcn_global_load_lds(
        (const __attribute__((address_space(1))) void*)g,
        (__attribute__((address_space(3))) void*)l, 16, 0, 0);
}

// ---------------------------------------------------------------------------
// fp32 -> bf16 bulk converts.
// ---------------------------------------------------------------------------
__device__ __forceinline__ void cvt8(const float* __restrict__ src,
                                     short* __restrict__ dst, int i) {
    const f32x4* p = (const f32x4*)src + (size_t)i * 2;
    const f32x4 u0 = p[0];
    const f32x4 u1 = p[1];
    short8 s;
    s[0] = f2bf(u0[0]); s[1] = f2bf(u0[1]); s[2] = f2bf(u0[2]); s[3] = f2bf(u0[3]);
    s[4] = f2bf(u1[0]); s[5] = f2bf(u1[1]); s[6] = f2bf(u1[2]); s[7] = f2bf(u1[3]);
    ((short8*)dst)[i] = s;
}

__global__ __launch_bounds__(256) void cvt_kernel(
    const float* __restrict__ src, short* __restrict__ dst, int n8)
{
    const int i = blockIdx.x * 256 + threadIdx.x;
    if (i >= n8) return;
    cvt8(src, dst, i);
}

// x (4096 blocks) + wq/wk/wv (512 blocks each) in one launch; grid 5632.
__global__ __launch_bounds__(256) void cvt4_kernel(
    const float* __restrict__ sx, short* __restrict__ dx,
    const float* __restrict__ s0, const float* __restrict__ s1,
    const float* __restrict__ s2, short* __restrict__ d0,
    short* __restrict__ d1, short* __restrict__ d2)
{
    const int bx = blockIdx.x;
    if (bx < 4096) {
        cvt8(sx, dx, bx * 256 + threadIdx.x);
    } else {
        const int which = (bx - 4096) >> 9;
        const int i = ((bx - 4096) & 511) * 256 + threadIdx.x;
        const float* s = which == 0 ? s0 : which == 1 ? s1 : s2;
        short* d = which == 0 ? d0 : which == 1 ? d1 : d2;
        cvt8(s, d, i);
    }
}

// attn-out (8M elems, 4096 blocks) + wo (1M elems, 512 blocks) in one launch.
__global__ __launch_bounds__(256) void cvt2_kernel(
    const float* __restrict__ s0, short* __restrict__ d0,
    const float* __restrict__ s1, short* __restrict__ d1)
{
    if (blockIdx.x < 4096) {
        cvt8(s0, d0, blockIdx.x * 256 + threadIdx.x);
    } else {
        cvt8(s1, d1, (blockIdx.x - 4096) * 256 + threadIdx.x);
    }
}

// ---------------------------------------------------------------------------
// GEMM body (m97 structure): out = A(8192 x 1024) * W^T + bias, bf16 in.
// 128x128 block tile, 4 waves each 64x64, BK=32. Staging via
// global_load_lds width 16 into linear LDS [128][32]. 2 barriers per K-step.
// layout 0/1 -> bf16 (B,H,L,dh); 2 -> bf16 (B,H,dh,L); 3 -> fp32 (M,1024).
// oscale multiplies (acc+bias) before store.
// ---------------------------------------------------------------------------
__device__ __forceinline__ void gemm_body(
    const short* __restrict__ A, const short* __restrict__ W,
    const float* __restrict__ bias, void* __restrict__ out,
    int layout, int m0, int n0, float oscale)
{
    __shared__ short As[128 * 32];
    __shared__ short Bs[128 * 32];

    const int t = threadIdx.x;
    const int wave = t >> 6, lane = t & 63;
    const int wm = (wave >> 1) * 64, wn = (wave & 1) * 64;
    const int l15 = lane & 15, quad = lane >> 4;

    const int r4 = lane >> 2;           // 0..15
    const int kc = (lane & 3) * 8;      // 0,8,16,24

    short* lA0 = &As[wave * 512 + lane * 8];
    short* lA1 = &As[2048 + wave * 512 + lane * 8];
    short* lB0 = &Bs[wave * 512 + lane * 8];
    short* lB1 = &Bs[2048 + wave * 512 + lane * 8];

    const short* gA0 = A + (size_t)(m0 + wave * 16 + r4) * 1024 + kc;
    const short* gA1 = gA0 + (size_t)64 * 1024;
    const short* gB0 = W + (size_t)(n0 + wave * 16 + r4) * 1024 + kc;
    const short* gB1 = gB0 + (size_t)64 * 1024;

    floatx4 acc[4][4];
#pragma unroll
    for (int i = 0; i < 4; i++)
#pragma unroll
        for (int j = 0; j < 4; j++) {
            acc[i][j][0] = 0.f; acc[i][j][1] = 0.f;
            acc[i][j][2] = 0.f; acc[i][j][3] = 0.f;
        }

    for (int kb = 0; kb < 1024; kb += 32) {
        gload_lds16(gA0 + kb, lA0);
        gload_lds16(gA1 + kb, lA1);
        gload_lds16(gB0 + kb, lB0);
        gload_lds16(gB1 + kb, lB1);
        __syncthreads();   // vmcnt(0) drain + barrier: LDS tile ready

        short8 af[4], bfr[4];
#pragma unroll
        for (int mi = 0; mi < 4; mi++)
            af[mi] = *(short8*)&As[(wm + mi * 16 + l15) * 32 + quad * 8];
#pragma unroll
        for (int ni = 0; ni < 4; ni++)
            bfr[ni] = *(short8*)&Bs[(wn + ni * 16 + l15) * 32 + quad * 8];
#pragma unroll
        for (int mi = 0; mi < 4; mi++)
#pragma unroll
            for (int ni = 0; ni < 4; ni++)
                acc[mi][ni] = MFMA16(af[mi], bfr[ni], acc[mi][ni]);

        __syncthreads();   // protect LDS from next K-step's staging
    }

    // Epilogue. C layout: col = lane&15, row = quad*4 + r.
#pragma unroll
    for (int ni = 0; ni < 4; ni++) {
        const int gn = n0 + wn + ni * 16 + l15;
        const float bv = bias[gn];
#pragma unroll
        for (int mi = 0; mi < 4; mi++) {
#pragma unroll
            for (int r = 0; r < 4; r++) {
                const int gm = m0 + wm + mi * 16 + quad * 4 + r;
                const float v = (acc[mi][ni][r] + bv) * oscale;
                if (layout == 3) {
                    ((float*)out)[(size_t)gm * 1024 + gn] = v;
                } else {
                    const int b = gm >> 11, l = gm & 2047;  // L = 2048
                    const int h = gn >> 6,  d = gn & 63;    // dh = 64
                    size_t idx;
                    if (layout == 2)
                        idx = ((size_t)(b * 16 + h) * 64 + d) * 2048 + l;
                    else
                        idx = ((size_t)(b * 16 + h) * 2048 + l) * 64 + d;
                    ((short*)out)[idx] = f2bf(v);
                }
            }
        }
    }
}

// fused QKV: grid (64, 24); blockIdx.y>>3 selects {Q,K,V} panel.
// Q panel is pre-scaled by SC = 0.125 * log2(e) (softmax scale folded in).
__global__ __launch_bounds__(256, 3) void qkv_kernel(
    const short* __restrict__ Xb,
    const short* __restrict__ Wq, const short* __restrict__ Wk,
    const short* __restrict__ Wv,
    const float* __restrict__ bq, const float* __restrict__ bk,
    const float* __restrict__ bv,
    short* __restrict__ Qo, short* __restrict__ Ko, short* __restrict__ Vo)
{
    const int chunk = blockIdx.y >> 3;            // 0=Q,1=K,2=V
    const int n0 = (blockIdx.y & 7) * 128;
    const short* W = chunk == 0 ? Wq : chunk == 1 ? Wk : Wv;
    const float* bs = chunk == 0 ? bq : chunk == 1 ? bk : bv;
    void* out = chunk == 0 ? (void*)Qo : chunk == 1 ? (void*)Ko : (void*)Vo;
    const float os = chunk == 0 ? 0.125f * 1.44269504f : 1.0f;
    gemm_body(Xb, W, bs, out, chunk, blockIdx.x * 128, n0, os);
}

__global__ __launch_bounds__(256, 3) void gemm_kernel(
    const short* __restrict__ A, const short* __restrict__ W,
    const float* __restrict__ bias, void* __restrict__ out, int layout)
{
    gemm_body(A, W, bias, out, layout, blockIdx.x * 128, blockIdx.y * 128, 1.0f);
}

// ---------------------------------------------------------------------------
// Attention (exact R13 kernel — passed twice at 144us). Q arrives pre-scaled
// by SC, so P = exp2(S + maskbias) directly. 512 blocks x 4 waves; each wave
// owns 4 q-tiles (64 rows). Swapped QK^T (mfma(K,Q)); P^T packed via
// v_cvt_pk_bf16_f32 -> ds_write_b64; mask as -1e9 accumulator seed; row sums
// via ones-column MFMA. XCD-affine: bh = blk & 63.
// Q,K bf16 (B,H,L,dh); VT bf16 (B,H,dh,L); mask int32; O fp32 (B,L,D).
// ---------------------------------------------------------------------------
__global__ __launch_bounds__(256, 2) void attn_kernel(
    const short* __restrict__ Q, const short* __restrict__ Kc,
    const short* __restrict__ VT, const int* __restrict__ mask,
    float* __restrict__ O)
{
    __shared__ short Plds_all[4][4][16 * 72];   // 36864 B

    const int blk = blockIdx.x;          // 512 blocks
    const int bh = blk & 63;             // same bh -> same XCD
    const int qg = blk >> 6;             // 0..7 (256 rows each)
    const int b = bh >> 4, h = bh & 15;
    const int t = threadIdx.x;
    const int wave = t >> 6, lane = t & 63;
    const int l15 = lane & 15, quad = lane >> 4;

    const short* Qb = Q  + (size_t)bh * 2048 * 64;
    const short* Kb = Kc + (size_t)bh * 2048 * 64;
    const short* Vb = VT + (size_t)bh * 64 * 2048;
    const int* mrow = mask + b * 2048;

    const int qbase = qg * 256 + wave * 64;

    short8 aq[4][2];
#pragma unroll
    for (int tt = 0; tt < 4; tt++) {
        const short* qp = Qb + (size_t)(qbase + tt * 16 + l15) * 64 + quad * 8;
        aq[tt][0] = *(const short8*)(qp);
        aq[tt][1] = *(const short8*)(qp + 32);
    }

    short8 vone;
#pragma unroll
    for (int j = 0; j < 8; j++) vone[j] = (short)0x3F80;

    floatx4 accO[4][5];
#pragma unroll
    for (int tt = 0; tt < 4; tt++)
#pragma unroll
        for (int ni = 0; ni < 5; ni++) {
            accO[tt][ni][0] = 0.f; accO[tt][ni][1] = 0.f;
            accO[tt][ni][2] = 0.f; accO[tt][ni][3] = 0.f;
        }

    for (int c0 = 0; c0 < 2048; c0 += 64) {
        short8 kreg[4][2];
#pragma unroll
        for (int g = 0; g < 4; g++) {
            const short* kp = Kb + (size_t)(c0 + g * 16 + l15) * 64 + quad * 8;
            kreg[g][0] = *(const short8*)(kp);
            kreg[g][1] = *(const short8*)(kp + 32);
        }
        f32x4 bias[4];
#pragma unroll
        for (int g = 0; g < 4; g++) {
            const int4v mv = *(const int4v*)&mrow[c0 + g * 16 + quad * 4];
#pragma unroll
            for (int r = 0; r < 4; r++) bias[g][r] = mv[r] ? -1e9f : 0.f;
        }
        short8 vreg[4][2];
#pragma unroll
        for (int ni = 0; ni < 4; ni++) {
            const short* vp = Vb + (size_t)(ni * 16 + l15) * 2048 + c0 + quad * 8;
            vreg[ni][0] = *(const short8*)(vp);
            vreg[ni][1] = *(const short8*)(vp + 32);
        }

#pragma unroll
        for (int tt = 0; tt < 4; tt++) {
            floatx4 s[4];
            __builtin_amdgcn_s_setprio(1);
#pragma unroll
            for (int g = 0; g < 4; g++) {
                floatx4 z = bias[g];
                z = MFMA16(kreg[g][0], aq[tt][0], z);
                s[g] = MFMA16(kreg[g][1], aq[tt][1], z);
            }
            __builtin_amdgcn_s_setprio(0);
            short* Pl = &Plds_all[wave][tt][0];
#pragma unroll
            for (int g = 0; g < 4; g++) {
                const float p0 = fast_exp2(s[g][0]);
                const float p1 = fast_exp2(s[g][1]);
                const float p2 = fast_exp2(s[g][2]);
                const float p3 = fast_exp2(s[g][3]);
                unsigned lo, hi;
                asm("v_cvt_pk_bf16_f32 %0, %1, %2" : "=v"(lo) : "v"(p0), "v"(p1));
                asm("v_cvt_pk_bf16_f32 %0, %1, %2" : "=v"(hi) : "v"(p2), "v"(p3));
                u32x2 w; w[0] = lo; w[1] = hi;
                *(u32x2*)&Pl[l15 * 72 + g * 16 + quad * 4] = w;
            }
        }

        asm volatile("s_waitcnt lgkmcnt(0)" ::: "memory");

#pragma unroll
        for (int tt = 0; tt < 4; tt++) {
            const short* Pl = &Plds_all[wave][tt][0];
            const short8 pa0 = *(const short8*)&Pl[l15 * 72 + quad * 8];
            const short8 pa1 = *(const short8*)&Pl[l15 * 72 + 32 + quad * 8];
            __builtin_amdgcn_s_setprio(1);
#pragma unroll
            for (int ni = 0; ni < 4; ni++) {
                accO[tt][ni] = MFMA16(pa0, vreg[ni][0], accO[tt][ni]);
                accO[tt][ni] = MFMA16(pa1, vreg[ni][1], accO[tt][ni]);
            }
            accO[tt][4] = MFMA16(pa0, vone, accO[tt][4]);
            accO[tt][4] = MFMA16(pa1, vone, accO[tt][4]);
            __builtin_amdgcn_s_setprio(0);
        }
    }

#pragma unroll
    for (int tt = 0; tt < 4; tt++) {
#pragma unroll
        for (int r = 0; r < 4; r++) {
            const float inv = 1.0f / fmaxf(accO[tt][4][r], 1e-30f);
            const int l = qbase + tt * 16 + quad * 4 + r;
#pragma unroll
            for (int ni = 0; ni < 4; ni++) {
                O[(size_t)(b * 2048 + l) * 1024 + h * 64 + ni * 16 + l15] =
                    accO[tt][ni][r] * inv;
            }
        }
    }
}

// ---------------------------------------------------------------------------
extern "C" void kernel_launch(void* const* d_in, const int* in_sizes, int n_in,
                              void* d_out, int out_size, void* d_ws, size_t ws_size,
                              hipStream_t stream)
{
    const float* x    = (const float*)d_in[0];
    const int*   mask = (const int*)d_in[1];
    const float* wq   = (const float*)d_in[2];
    const float* bq   = (const float*)d_in[3];
    const float* wk   = (const float*)d_in[4];
    const float* bk   = (const float*)d_in[5];
    const float* wv   = (const float*)d_in[6];
    const float* bv   = (const float*)d_in[7];
    const float* wo   = (const float*)d_in[8];
    const float* bo   = (const float*)d_in[9];
    float* out = (float*)d_out;   // fp32 output (8M floats)

    // ws (48 MiB): [Qbuf bf16 16MB][Kbuf bf16 16MB][Vt bf16 16MB]
    short* Qbuf = (short*)d_ws;
    short* Kbuf = Qbuf + (size_t)8 * 1024 * 1024;
    short* Vt   = Kbuf + (size_t)8 * 1024 * 1024;

    // d_out doubles as scratch until attn writes it.
    short* Xb  = (short*)d_out;
    short* Wqb = Xb  + (size_t)8 * 1024 * 1024;
    short* Wkb = Wqb + (size_t)1024 * 1024;
    short* Wvb = Wkb + (size_t)1024 * 1024;

    dim3 block(256);

    // fp32 -> bf16: x + wq/wk/wv in one launch.
    cvt4_kernel<<<dim3(5632), block, 0, stream>>>(
        x, Xb, wq, wk, wv, Wqb, Wkb, Wvb);

    qkv_kernel<<<dim3(64, 24), block, 0, stream>>>(
        Xb, Wqb, Wkb, Wvb, bq, bk, bv, Qbuf, Kbuf, Vt);

    attn_kernel<<<dim3(512), block, 0, stream>>>(Qbuf, Kbuf, Vt, mask, out);

    short* Ob  = Qbuf;
    short* Wob = Kbuf;
    cvt2_kernel<<<dim3(4608), block, 0, stream>>>(out, Ob, wo, Wob);

    gemm_kernel<<<dim3(64, 8), block, 0, stream>>>(Ob, Wob, bo, out, 3);
}

// Round 11
// 355.552 us; speedup vs baseline: 2.0051x; 1.0178x over previous
//
#include <hip/hip_runtime.h>

// ---------------------------------------------------------------------------
// MultiHeadSelfAttention: B=4, L=2048, D=1024, H=16, dh=64.
// R18 = exact R13 (best measured: 354.3us). The R17 cvt4 merge regressed
// ~8us (prediction failed -> reverted). attn = proven kernel (passed 3x,
// ~144us, VGPR 116). GEMM = m97 structure, gload_lds16, fused QKV,
// Q pre-scaled by 0.125*log2(e). Ladder this session: 595 -> 531 -> 378 ->
// 357 -> 354 (R13) with failed excursions R12/R14/R15/R16/R17 documented.
// ---------------------------------------------------------------------------

typedef __attribute__((ext_vector_type(8))) short short8;   // 8 bf16 = 4 VGPR
typedef __attribute__((ext_vector_type(4))) float f32x4;
typedef __attribute__((ext_vector_type(4))) float floatx4;
typedef __attribute__((ext_vector_type(4))) int int4v;
typedef __attribute__((ext_vector_type(2))) unsigned int u32x2;

#define MFMA16(a, b, c) __builtin_amdgcn_mfma_f32_16x16x32_bf16((a), (b), (c), 0, 0, 0)

__device__ __forceinline__ short f2bf(float f) {
    unsigned u = __float_as_uint(f);
    u += 0x7FFF + ((u >> 16) & 1);   // round-to-nearest-even
    return (short)(u >> 16);
}

__device__ __forceinline__ float fast_exp2(float x) {
#if __has_builtin(__builtin_amdgcn_exp2f)
    return __builtin_amdgcn_exp2f(x);   // single v_exp_f32
#else
    return exp2f(x);
#endif
}

// async global -> LDS, 16 B per lane (global_load_lds_dwordx4).
__device__ __forceinline__ void gload_lds16(const short* g, short* l) {
    __builtin_amdgcn_global_load_lds(
        (const __attribute__((address_space(1))) void*)g,
        (__attribute__((address_space(3))) void*)l, 16, 0, 0);
}

// ---------------------------------------------------------------------------
// fp32 -> bf16 bulk converts.
// ---------------------------------------------------------------------------
__device__ __forceinline__ void cvt8(const float* __restrict__ src,
                                     short* __restrict__ dst, int i) {
    const f32x4* p = (const f32x4*)src + (size_t)i * 2;
    const f32x4 u0 = p[0];
    const f32x4 u1 = p[1];
    short8 s;
    s[0] = f2bf(u0[0]); s[1] = f2bf(u0[1]); s[2] = f2bf(u0[2]); s[3] = f2bf(u0[3]);
    s[4] = f2bf(u1[0]); s[5] = f2bf(u1[1]); s[6] = f2bf(u1[2]); s[7] = f2bf(u1[3]);
    ((short8*)dst)[i] = s;
}

__global__ __launch_bounds__(256) void cvt_kernel(
    const float* __restrict__ src, short* __restrict__ dst, int n8)
{
    const int i = blockIdx.x * 256 + threadIdx.x;
    if (i >= n8) return;
    cvt8(src, dst, i);
}

// three 1024x1024 weight matrices in one launch; grid 3*512, exact.
__global__ __launch_bounds__(256) void cvt3_kernel(
    const float* __restrict__ s0, const float* __restrict__ s1,
    const float* __restrict__ s2, short* __restrict__ d0,
    short* __restrict__ d1, short* __restrict__ d2)
{
    const int which = blockIdx.x >> 9;
    const int i = (blockIdx.x & 511) * 256 + threadIdx.x;
    const float* s = which == 0 ? s0 : which == 1 ? s1 : s2;
    short* d = which == 0 ? d0 : which == 1 ? d1 : d2;
    cvt8(s, d, i);
}

// attn-out (8M elems, 4096 blocks) + wo (1M elems, 512 blocks) in one launch.
__global__ __launch_bounds__(256) void cvt2_kernel(
    const float* __restrict__ s0, short* __restrict__ d0,
    const float* __restrict__ s1, short* __restrict__ d1)
{
    if (blockIdx.x < 4096) {
        cvt8(s0, d0, blockIdx.x * 256 + threadIdx.x);
    } else {
        cvt8(s1, d1, (blockIdx.x - 4096) * 256 + threadIdx.x);
    }
}

// ---------------------------------------------------------------------------
// GEMM body (m97 structure): out = A(8192 x 1024) * W^T + bias, bf16 in.
// 128x128 block tile, 4 waves each 64x64, BK=32. Staging via
// global_load_lds width 16 into linear LDS [128][32]. 2 barriers per K-step.
// layout 0/1 -> bf16 (B,H,L,dh); 2 -> bf16 (B,H,dh,L); 3 -> fp32 (M,1024).
// oscale multiplies (acc+bias) before store.
// ---------------------------------------------------------------------------
__device__ __forceinline__ void gemm_body(
    const short* __restrict__ A, const short* __restrict__ W,
    const float* __restrict__ bias, void* __restrict__ out,
    int layout, int m0, int n0, float oscale)
{
    __shared__ short As[128 * 32];
    __shared__ short Bs[128 * 32];

    const int t = threadIdx.x;
    const int wave = t >> 6, lane = t & 63;
    const int wm = (wave >> 1) * 64, wn = (wave & 1) * 64;
    const int l15 = lane & 15, quad = lane >> 4;

    const int r4 = lane >> 2;           // 0..15
    const int kc = (lane & 3) * 8;      // 0,8,16,24

    short* lA0 = &As[wave * 512 + lane * 8];
    short* lA1 = &As[2048 + wave * 512 + lane * 8];
    short* lB0 = &Bs[wave * 512 + lane * 8];
    short* lB1 = &Bs[2048 + wave * 512 + lane * 8];

    const short* gA0 = A + (size_t)(m0 + wave * 16 + r4) * 1024 + kc;
    const short* gA1 = gA0 + (size_t)64 * 1024;
    const short* gB0 = W + (size_t)(n0 + wave * 16 + r4) * 1024 + kc;
    const short* gB1 = gB0 + (size_t)64 * 1024;

    floatx4 acc[4][4];
#pragma unroll
    for (int i = 0; i < 4; i++)
#pragma unroll
        for (int j = 0; j < 4; j++) {
            acc[i][j][0] = 0.f; acc[i][j][1] = 0.f;
            acc[i][j][2] = 0.f; acc[i][j][3] = 0.f;
        }

    for (int kb = 0; kb < 1024; kb += 32) {
        gload_lds16(gA0 + kb, lA0);
        gload_lds16(gA1 + kb, lA1);
        gload_lds16(gB0 + kb, lB0);
        gload_lds16(gB1 + kb, lB1);
        __syncthreads();   // vmcnt(0) drain + barrier: LDS tile ready

        short8 af[4], bfr[4];
#pragma unroll
        for (int mi = 0; mi < 4; mi++)
            af[mi] = *(short8*)&As[(wm + mi * 16 + l15) * 32 + quad * 8];
#pragma unroll
        for (int ni = 0; ni < 4; ni++)
            bfr[ni] = *(short8*)&Bs[(wn + ni * 16 + l15) * 32 + quad * 8];
#pragma unroll
        for (int mi = 0; mi < 4; mi++)
#pragma unroll
            for (int ni = 0; ni < 4; ni++)
                acc[mi][ni] = MFMA16(af[mi], bfr[ni], acc[mi][ni]);

        __syncthreads();   // protect LDS from next K-step's staging
    }

    // Epilogue. C layout: col = lane&15, row = quad*4 + r.
#pragma unroll
    for (int ni = 0; ni < 4; ni++) {
        const int gn = n0 + wn + ni * 16 + l15;
        const float bv = bias[gn];
#pragma unroll
        for (int mi = 0; mi < 4; mi++) {
#pragma unroll
            for (int r = 0; r < 4; r++) {
                const int gm = m0 + wm + mi * 16 + quad * 4 + r;
                const float v = (acc[mi][ni][r] + bv) * oscale;
                if (layout == 3) {
                    ((float*)out)[(size_t)gm * 1024 + gn] = v;
                } else {
                    const int b = gm >> 11, l = gm & 2047;  // L = 2048
                    const int h = gn >> 6,  d = gn & 63;    // dh = 64
                    size_t idx;
                    if (layout == 2)
                        idx = ((size_t)(b * 16 + h) * 64 + d) * 2048 + l;
                    else
                        idx = ((size_t)(b * 16 + h) * 2048 + l) * 64 + d;
                    ((short*)out)[idx] = f2bf(v);
                }
            }
        }
    }
}

// fused QKV: grid (64, 24); blockIdx.y>>3 selects {Q,K,V} panel.
// Q panel is pre-scaled by SC = 0.125 * log2(e) (softmax scale folded in).
__global__ __launch_bounds__(256, 3) void qkv_kernel(
    const short* __restrict__ Xb,
    const short* __restrict__ Wq, const short* __restrict__ Wk,
    const short* __restrict__ Wv,
    const float* __restrict__ bq, const float* __restrict__ bk,
    const float* __restrict__ bv,
    short* __restrict__ Qo, short* __restrict__ Ko, short* __restrict__ Vo)
{
    const int chunk = blockIdx.y >> 3;            // 0=Q,1=K,2=V
    const int n0 = (blockIdx.y & 7) * 128;
    const short* W = chunk == 0 ? Wq : chunk == 1 ? Wk : Wv;
    const float* bs = chunk == 0 ? bq : chunk == 1 ? bk : bv;
    void* out = chunk == 0 ? (void*)Qo : chunk == 1 ? (void*)Ko : (void*)Vo;
    const float os = chunk == 0 ? 0.125f * 1.44269504f : 1.0f;
    gemm_body(Xb, W, bs, out, chunk, blockIdx.x * 128, n0, os);
}

__global__ __launch_bounds__(256, 3) void gemm_kernel(
    const short* __restrict__ A, const short* __restrict__ W,
    const float* __restrict__ bias, void* __restrict__ out, int layout)
{
    gemm_body(A, W, bias, out, layout, blockIdx.x * 128, blockIdx.y * 128, 1.0f);
}

// ---------------------------------------------------------------------------
// Attention (proven kernel — 3 passing runs at ~144us). Q arrives pre-scaled
// by SC, so P = exp2(S + maskbias) directly. 512 blocks x 4 waves; each wave
// owns 4 q-tiles (64 rows). Swapped QK^T (mfma(K,Q)); P^T packed via
// v_cvt_pk_bf16_f32 -> ds_write_b64; mask as -1e9 accumulator seed; row sums
// via ones-column MFMA. XCD-affine: bh = blk & 63.
// Q,K bf16 (B,H,L,dh); VT bf16 (B,H,dh,L); mask int32; O fp32 (B,L,D).
// ---------------------------------------------------------------------------
__global__ __launch_bounds__(256, 2) void attn_kernel(
    const short* __restrict__ Q, const short* __restrict__ Kc,
    const short* __restrict__ VT, const int* __restrict__ mask,
    float* __restrict__ O)
{
    __shared__ short Plds_all[4][4][16 * 72];   // 36864 B

    const int blk = blockIdx.x;          // 512 blocks
    const int bh = blk & 63;             // same bh -> same XCD
    const int qg = blk >> 6;             // 0..7 (256 rows each)
    const int b = bh >> 4, h = bh & 15;
    const int t = threadIdx.x;
    const int wave = t >> 6, lane = t & 63;
    const int l15 = lane & 15, quad = lane >> 4;

    const short* Qb = Q  + (size_t)bh * 2048 * 64;
    const short* Kb = Kc + (size_t)bh * 2048 * 64;
    const short* Vb = VT + (size_t)bh * 64 * 2048;
    const int* mrow = mask + b * 2048;

    const int qbase = qg * 256 + wave * 64;

    short8 aq[4][2];
#pragma unroll
    for (int tt = 0; tt < 4; tt++) {
        const short* qp = Qb + (size_t)(qbase + tt * 16 + l15) * 64 + quad * 8;
        aq[tt][0] = *(const short8*)(qp);
        aq[tt][1] = *(const short8*)(qp + 32);
    }

    short8 vone;
#pragma unroll
    for (int j = 0; j < 8; j++) vone[j] = (short)0x3F80;

    floatx4 accO[4][5];
#pragma unroll
    for (int tt = 0; tt < 4; tt++)
#pragma unroll
        for (int ni = 0; ni < 5; ni++) {
            accO[tt][ni][0] = 0.f; accO[tt][ni][1] = 0.f;
            accO[tt][ni][2] = 0.f; accO[tt][ni][3] = 0.f;
        }

    for (int c0 = 0; c0 < 2048; c0 += 64) {
        short8 kreg[4][2];
#pragma unroll
        for (int g = 0; g < 4; g++) {
            const short* kp = Kb + (size_t)(c0 + g * 16 + l15) * 64 + quad * 8;
            kreg[g][0] = *(const short8*)(kp);
            kreg[g][1] = *(const short8*)(kp + 32);
        }
        f32x4 bias[4];
#pragma unroll
        for (int g = 0; g < 4; g++) {
            const int4v mv = *(const int4v*)&mrow[c0 + g * 16 + quad * 4];
#pragma unroll
            for (int r = 0; r < 4; r++) bias[g][r] = mv[r] ? -1e9f : 0.f;
        }
        short8 vreg[4][2];
#pragma unroll
        for (int ni = 0; ni < 4; ni++) {
            const short* vp = Vb + (size_t)(ni * 16 + l15) * 2048 + c0 + quad * 8;
            vreg[ni][0] = *(const short8*)(vp);
            vreg[ni][1] = *(const short8*)(vp + 32);
        }

#pragma unroll
        for (int tt = 0; tt < 4; tt++) {
            floatx4 s[4];
            __builtin_amdgcn_s_setprio(1);
#pragma unroll
            for (int g = 0; g < 4; g++) {
                floatx4 z = bias[g];
                z = MFMA16(kreg[g][0], aq[tt][0], z);
                s[g] = MFMA16(kreg[g][1], aq[tt][1], z);
            }
            __builtin_amdgcn_s_setprio(0);
            short* Pl = &Plds_all[wave][tt][0];
#pragma unroll
            for (int g = 0; g < 4; g++) {
                const float p0 = fast_exp2(s[g][0]);
                const float p1 = fast_exp2(s[g][1]);
                const float p2 = fast_exp2(s[g][2]);
                const float p3 = fast_exp2(s[g][3]);
                unsigned lo, hi;
                asm("v_cvt_pk_bf16_f32 %0, %1, %2" : "=v"(lo) : "v"(p0), "v"(p1));
                asm("v_cvt_pk_bf16_f32 %0, %1, %2" : "=v"(hi) : "v"(p2), "v"(p3));
                u32x2 w; w[0] = lo; w[1] = hi;
                *(u32x2*)&Pl[l15 * 72 + g * 16 + quad * 4] = w;
            }
        }

        asm volatile("s_waitcnt lgkmcnt(0)" ::: "memory");

#pragma unroll
        for (int tt = 0; tt < 4; tt++) {
            const short* Pl = &Plds_all[wave][tt][0];
            const short8 pa0 = *(const short8*)&Pl[l15 * 72 + quad * 8];
            const short8 pa1 = *(const short8*)&Pl[l15 * 72 + 32 + quad * 8];
            __builtin_amdgcn_s_setprio(1);
#pragma unroll
            for (int ni = 0; ni < 4; ni++) {
                accO[tt][ni] = MFMA16(pa0, vreg[ni][0], accO[tt][ni]);
                accO[tt][ni] = MFMA16(pa1, vreg[ni][1], accO[tt][ni]);
            }
            accO[tt][4] = MFMA16(pa0, vone, accO[tt][4]);
            accO[tt][4] = MFMA16(pa1, vone, accO[tt][4]);
            __builtin_amdgcn_s_setprio(0);
        }
    }

#pragma unroll
    for (int tt = 0; tt < 4; tt++) {
#pragma unroll
        for (int r = 0; r < 4; r++) {
            const float inv = 1.0f / fmaxf(accO[tt][4][r], 1e-30f);
            const int l = qbase + tt * 16 + quad * 4 + r;
#pragma unroll
            for (int ni = 0; ni < 4; ni++) {
                O[(size_t)(b * 2048 + l) * 1024 + h * 64 + ni * 16 + l15] =
                    accO[tt][ni][r] * inv;
            }
        }
    }
}

// ---------------------------------------------------------------------------
extern "C" void kernel_launch(void* const* d_in, const int* in_sizes, int n_in,
                              void* d_out, int out_size, void* d_ws, size_t ws_size,
                              hipStream_t stream)
{
    const float* x    = (const float*)d_in[0];
    const int*   mask = (const int*)d_in[1];
    const float* wq   = (const float*)d_in[2];
    const float* bq   = (const float*)d_in[3];
    const float* wk   = (const float*)d_in[4];
    const float* bk   = (const float*)d_in[5];
    const float* wv   = (const float*)d_in[6];
    const float* bv   = (const float*)d_in[7];
    const float* wo   = (const float*)d_in[8];
    const float* bo   = (const float*)d_in[9];
    float* out = (float*)d_out;   // fp32 output (8M floats)

    // ws (48 MiB): [Qbuf bf16 16MB][Kbuf bf16 16MB][Vt bf16 16MB]
    short* Qbuf = (short*)d_ws;
    short* Kbuf = Qbuf + (size_t)8 * 1024 * 1024;
    short* Vt   = Kbuf + (size_t)8 * 1024 * 1024;

    // d_out doubles as scratch until attn writes it.
    short* Xb  = (short*)d_out;
    short* Wqb = Xb  + (size_t)8 * 1024 * 1024;
    short* Wkb = Wqb + (size_t)1024 * 1024;
    short* Wvb = Wkb + (size_t)1024 * 1024;

    dim3 block(256);

    cvt_kernel<<<dim3(4096), block, 0, stream>>>(x, Xb, 1024 * 1024);
    cvt3_kernel<<<dim3(1536), block, 0, stream>>>(wq, wk, wv, Wqb, Wkb, Wvb);

    qkv_kernel<<<dim3(64, 24), block, 0, stream>>>(
        Xb, Wqb, Wkb, Wvb, bq, bk, bv, Qbuf, Kbuf, Vt);

    attn_kernel<<<dim3(512), block, 0, stream>>>(Qbuf, Kbuf, Vt, mask, out);

    short* Ob  = Qbuf;
    short* Wob = Kbuf;
    cvt2_kernel<<<dim3(4608), block, 0, stream>>>(out, Ob, wo, Wob);

    gemm_kernel<<<dim3(64, 8), block, 0, stream>>>(Ob, Wob, bo, out, 3);
}

// Round 12
// 349.554 us; speedup vs baseline: 2.0395x; 1.0172x over previous
//
#include <hip/hip_runtime.h>

// ---------------------------------------------------------------------------
// MultiHeadSelfAttention: B=4, L=2048, D=1024, H=16, dh=64.
// R19: delete the attn-out fp32 round-trip. attn's epilogue writes bf16
// IN-PLACE into Qbuf ((B,H,L,dh) layout) — each block's Q rows are read only
// in its own prologue and by no other block, so the region is self-owned
// (static ownership, no timing assumption). cvt2 (48MB traffic) replaced by
// a 512-block wo-only convert. Final GEMM reads A via new layout 4
// ((B,H,L,dh) bf16); numerics identical (same f2bf of the same fp32 value).
// attn compute loop and GEMM structure otherwise byte-identical to R13/R18.
// ---------------------------------------------------------------------------

typedef __attribute__((ext_vector_type(8))) short short8;   // 8 bf16 = 4 VGPR
typedef __attribute__((ext_vector_type(4))) float f32x4;
typedef __attribute__((ext_vector_type(4))) float floatx4;
typedef __attribute__((ext_vector_type(4))) int int4v;
typedef __attribute__((ext_vector_type(2))) unsigned int u32x2;

#define MFMA16(a, b, c) __builtin_amdgcn_mfma_f32_16x16x32_bf16((a), (b), (c), 0, 0, 0)

__device__ __forceinline__ short f2bf(float f) {
    unsigned u = __float_as_uint(f);
    u += 0x7FFF + ((u >> 16) & 1);   // round-to-nearest-even
    return (short)(u >> 16);
}

__device__ __forceinline__ float fast_exp2(float x) {
#if __has_builtin(__builtin_amdgcn_exp2f)
    return __builtin_amdgcn_exp2f(x);   // single v_exp_f32
#else
    return exp2f(x);
#endif
}

// async global -> LDS, 16 B per lane (global_load_lds_dwordx4).
__device__ __forceinline__ void gload_lds16(const short* g, short* l) {
    __builtin_amdgcn_global_load_lds(
        (const __attribute__((address_space(1))) void*)g,
        (__attribute__((address_space(3))) void*)l, 16, 0, 0);
}

// ---------------------------------------------------------------------------
// fp32 -> bf16 bulk converts.
// ---------------------------------------------------------------------------
__device__ __forceinline__ void cvt8(const float* __restrict__ src,
                                     short* __restrict__ dst, int i) {
    const f32x4* p = (const f32x4*)src + (size_t)i * 2;
    const f32x4 u0 = p[0];
    const f32x4 u1 = p[1];
    short8 s;
    s[0] = f2bf(u0[0]); s[1] = f2bf(u0[1]); s[2] = f2bf(u0[2]); s[3] = f2bf(u0[3]);
    s[4] = f2bf(u1[0]); s[5] = f2bf(u1[1]); s[6] = f2bf(u1[2]); s[7] = f2bf(u1[3]);
    ((short8*)dst)[i] = s;
}

__global__ __launch_bounds__(256) void cvt_kernel(
    const float* __restrict__ src, short* __restrict__ dst, int n8)
{
    const int i = blockIdx.x * 256 + threadIdx.x;
    if (i >= n8) return;
    cvt8(src, dst, i);
}

// three 1024x1024 weight matrices in one launch; grid 3*512, exact.
__global__ __launch_bounds__(256) void cvt3_kernel(
    const float* __restrict__ s0, const float* __restrict__ s1,
    const float* __restrict__ s2, short* __restrict__ d0,
    short* __restrict__ d1, short* __restrict__ d2)
{
    const int which = blockIdx.x >> 9;
    const int i = (blockIdx.x & 511) * 256 + threadIdx.x;
    const float* s = which == 0 ? s0 : which == 1 ? s1 : s2;
    short* d = which == 0 ? d0 : which == 1 ? d1 : d2;
    cvt8(s, d, i);
}

// ---------------------------------------------------------------------------
// GEMM body (m97 structure): out = A(8192 x 1024) * W^T + bias, bf16 in.
// 128x128 block tile, 4 waves each 64x64, BK=32. Staging via
// global_load_lds width 16 into linear LDS [128][32]. 2 barriers per K-step.
// layout 0/1 -> out bf16 (B,H,L,dh); 2 -> out bf16 (B,H,dh,L);
// 3 -> out fp32 (M,1024); 4 -> out fp32 (M,1024) with A read from
// (B,H,L,dh) bf16: A(m,k) at b*2097152 + (k>>6)*131072 + l*64 + (k&63),
// b=m>>11, l=m&2047. Tiles (128 rows, m0 multiple of 128) never cross the
// L boundary; staged 8-chunks never cross dh=64 ((kb&63)+kc <= 56).
// oscale multiplies (acc+bias) before store.
// ---------------------------------------------------------------------------
__device__ __forceinline__ void gemm_body(
    const short* __restrict__ A, const short* __restrict__ W,
    const float* __restrict__ bias, void* __restrict__ out,
    int layout, int m0, int n0, float oscale)
{
    __shared__ short As[128 * 32];
    __shared__ short Bs[128 * 32];

    const int t = threadIdx.x;
    const int wave = t >> 6, lane = t & 63;
    const int wm = (wave >> 1) * 64, wn = (wave & 1) * 64;
    const int l15 = lane & 15, quad = lane >> 4;

    const int r4 = lane >> 2;           // 0..15
    const int kc = (lane & 3) * 8;      // 0,8,16,24

    short* lA0 = &As[wave * 512 + lane * 8];
    short* lA1 = &As[2048 + wave * 512 + lane * 8];
    short* lB0 = &Bs[wave * 512 + lane * 8];
    short* lB1 = &Bs[2048 + wave * 512 + lane * 8];

    const short* gA0;
    const short* gA1;
    if (layout == 4) {
        const int mA = m0 + wave * 16 + r4;
        const int bb = mA >> 11, ll = mA & 2047;
        gA0 = A + (size_t)bb * 2097152 + (size_t)ll * 64 + kc;
        gA1 = gA0 + 64 * 64;   // row +64 -> l +64 (same b within a tile)
    } else {
        gA0 = A + (size_t)(m0 + wave * 16 + r4) * 1024 + kc;
        gA1 = gA0 + (size_t)64 * 1024;
    }
    const short* gB0 = W + (size_t)(n0 + wave * 16 + r4) * 1024 + kc;
    const short* gB1 = gB0 + (size_t)64 * 1024;

    floatx4 acc[4][4];
#pragma unroll
    for (int i = 0; i < 4; i++)
#pragma unroll
        for (int j = 0; j < 4; j++) {
            acc[i][j][0] = 0.f; acc[i][j][1] = 0.f;
            acc[i][j][2] = 0.f; acc[i][j][3] = 0.f;
        }

    for (int kb = 0; kb < 1024; kb += 32) {
        const size_t aoff = (layout == 4)
            ? ((size_t)(kb >> 6) * 131072 + (size_t)(kb & 63))
            : (size_t)kb;
        gload_lds16(gA0 + aoff, lA0);
        gload_lds16(gA1 + aoff, lA1);
        gload_lds16(gB0 + kb, lB0);
        gload_lds16(gB1 + kb, lB1);
        __syncthreads();   // vmcnt(0) drain + barrier: LDS tile ready

        short8 af[4], bfr[4];
#pragma unroll
        for (int mi = 0; mi < 4; mi++)
            af[mi] = *(short8*)&As[(wm + mi * 16 + l15) * 32 + quad * 8];
#pragma unroll
        for (int ni = 0; ni < 4; ni++)
            bfr[ni] = *(short8*)&Bs[(wn + ni * 16 + l15) * 32 + quad * 8];
#pragma unroll
        for (int mi = 0; mi < 4; mi++)
#pragma unroll
            for (int ni = 0; ni < 4; ni++)
                acc[mi][ni] = MFMA16(af[mi], bfr[ni], acc[mi][ni]);

        __syncthreads();   // protect LDS from next K-step's staging
    }

    // Epilogue. C layout: col = lane&15, row = quad*4 + r.
#pragma unroll
    for (int ni = 0; ni < 4; ni++) {
        const int gn = n0 + wn + ni * 16 + l15;
        const float bv = bias[gn];
#pragma unroll
        for (int mi = 0; mi < 4; mi++) {
#pragma unroll
            for (int r = 0; r < 4; r++) {
                const int gm = m0 + wm + mi * 16 + quad * 4 + r;
                const float v = (acc[mi][ni][r] + bv) * oscale;
                if (layout >= 3) {
                    ((float*)out)[(size_t)gm * 1024 + gn] = v;
                } else {
                    const int b = gm >> 11, l = gm & 2047;  // L = 2048
                    const int h = gn >> 6,  d = gn & 63;    // dh = 64
                    size_t idx;
                    if (layout == 2)
                        idx = ((size_t)(b * 16 + h) * 64 + d) * 2048 + l;
                    else
                        idx = ((size_t)(b * 16 + h) * 2048 + l) * 64 + d;
                    ((short*)out)[idx] = f2bf(v);
                }
            }
        }
    }
}

// fused QKV: grid (64, 24); blockIdx.y>>3 selects {Q,K,V} panel.
// Q panel is pre-scaled by SC = 0.125 * log2(e) (softmax scale folded in).
__global__ __launch_bounds__(256, 3) void qkv_kernel(
    const short* __restrict__ Xb,
    const short* __restrict__ Wq, const short* __restrict__ Wk,
    const short* __restrict__ Wv,
    const float* __restrict__ bq, const float* __restrict__ bk,
    const float* __restrict__ bv,
    short* __restrict__ Qo, short* __restrict__ Ko, short* __restrict__ Vo)
{
    const int chunk = blockIdx.y >> 3;            // 0=Q,1=K,2=V
    const int n0 = (blockIdx.y & 7) * 128;
    const short* W = chunk == 0 ? Wq : chunk == 1 ? Wk : Wv;
    const float* bs = chunk == 0 ? bq : chunk == 1 ? bk : bv;
    void* out = chunk == 0 ? (void*)Qo : chunk == 1 ? (void*)Ko : (void*)Vo;
    const float os = chunk == 0 ? 0.125f * 1.44269504f : 1.0f;
    gemm_body(Xb, W, bs, out, chunk, blockIdx.x * 128, n0, os);
}

__global__ __launch_bounds__(256, 3) void gemm_kernel(
    const short* __restrict__ A, const short* __restrict__ W,
    const float* __restrict__ bias, void* __restrict__ out, int layout)
{
    gemm_body(A, W, bias, out, layout, blockIdx.x * 128, blockIdx.y * 128, 1.0f);
}

// ---------------------------------------------------------------------------
// Attention (compute loop identical to the proven R13 kernel). Q arrives
// pre-scaled by SC, so P = exp2(S + maskbias) directly. 512 blocks x 4
// waves; each wave owns 4 q-tiles (64 rows). Swapped QK^T (mfma(K,Q)); P^T
// packed via v_cvt_pk_bf16_f32 -> ds_write_b64; mask as -1e9 accumulator
// seed; row sums via ones-column MFMA. XCD-affine: bh = blk & 63.
// NEW (R19): epilogue writes bf16 IN-PLACE into QO ((B,H,L,dh)); each
// wave writes exactly the rows whose Q it loaded in its own prologue, and
// no other block ever reads those rows -> no inter-block hazard.
// QO bf16 in/out (B,H,L,dh); K bf16 (B,H,L,dh); VT bf16 (B,H,dh,L);
// mask int32.
// ---------------------------------------------------------------------------
__global__ __launch_bounds__(256, 2) void attn_kernel(
    short* QO, const short* __restrict__ Kc,
    const short* __restrict__ VT, const int* __restrict__ mask)
{
    __shared__ short Plds_all[4][4][16 * 72];   // 36864 B

    const int blk = blockIdx.x;          // 512 blocks
    const int bh = blk & 63;             // same bh -> same XCD
    const int qg = blk >> 6;             // 0..7 (256 rows each)
    const int b = bh >> 4;
    const int t = threadIdx.x;
    const int wave = t >> 6, lane = t & 63;
    const int l15 = lane & 15, quad = lane >> 4;

    short* Qb = QO + (size_t)bh * 2048 * 64;
    const short* Kb = Kc + (size_t)bh * 2048 * 64;
    const short* Vb = VT + (size_t)bh * 64 * 2048;
    const int* mrow = mask + b * 2048;

    const int qbase = qg * 256 + wave * 64;

    short8 aq[4][2];
#pragma unroll
    for (int tt = 0; tt < 4; tt++) {
        const short* qp = Qb + (size_t)(qbase + tt * 16 + l15) * 64 + quad * 8;
        aq[tt][0] = *(const short8*)(qp);
        aq[tt][1] = *(const short8*)(qp + 32);
    }

    short8 vone;
#pragma unroll
    for (int j = 0; j < 8; j++) vone[j] = (short)0x3F80;

    floatx4 accO[4][5];
#pragma unroll
    for (int tt = 0; tt < 4; tt++)
#pragma unroll
        for (int ni = 0; ni < 5; ni++) {
            accO[tt][ni][0] = 0.f; accO[tt][ni][1] = 0.f;
            accO[tt][ni][2] = 0.f; accO[tt][ni][3] = 0.f;
        }

    for (int c0 = 0; c0 < 2048; c0 += 64) {
        short8 kreg[4][2];
#pragma unroll
        for (int g = 0; g < 4; g++) {
            const short* kp = Kb + (size_t)(c0 + g * 16 + l15) * 64 + quad * 8;
            kreg[g][0] = *(const short8*)(kp);
            kreg[g][1] = *(const short8*)(kp + 32);
        }
        f32x4 bias[4];
#pragma unroll
        for (int g = 0; g < 4; g++) {
            const int4v mv = *(const int4v*)&mrow[c0 + g * 16 + quad * 4];
#pragma unroll
            for (int r = 0; r < 4; r++) bias[g][r] = mv[r] ? -1e9f : 0.f;
        }
        short8 vreg[4][2];
#pragma unroll
        for (int ni = 0; ni < 4; ni++) {
            const short* vp = Vb + (size_t)(ni * 16 + l15) * 2048 + c0 + quad * 8;
            vreg[ni][0] = *(const short8*)(vp);
            vreg[ni][1] = *(const short8*)(vp + 32);
        }

#pragma unroll
        for (int tt = 0; tt < 4; tt++) {
            floatx4 s[4];
            __builtin_amdgcn_s_setprio(1);
#pragma unroll
            for (int g = 0; g < 4; g++) {
                floatx4 z = bias[g];
                z = MFMA16(kreg[g][0], aq[tt][0], z);
                s[g] = MFMA16(kreg[g][1], aq[tt][1], z);
            }
            __builtin_amdgcn_s_setprio(0);
            short* Pl = &Plds_all[wave][tt][0];
#pragma unroll
            for (int g = 0; g < 4; g++) {
                const float p0 = fast_exp2(s[g][0]);
                const float p1 = fast_exp2(s[g][1]);
                const float p2 = fast_exp2(s[g][2]);
                const float p3 = fast_exp2(s[g][3]);
                unsigned lo, hi;
                asm("v_cvt_pk_bf16_f32 %0, %1, %2" : "=v"(lo) : "v"(p0), "v"(p1));
                asm("v_cvt_pk_bf16_f32 %0, %1, %2" : "=v"(hi) : "v"(p2), "v"(p3));
                u32x2 w; w[0] = lo; w[1] = hi;
                *(u32x2*)&Pl[l15 * 72 + g * 16 + quad * 4] = w;
            }
        }

        asm volatile("s_waitcnt lgkmcnt(0)" ::: "memory");

#pragma unroll
        for (int tt = 0; tt < 4; tt++) {
            const short* Pl = &Plds_all[wave][tt][0];
            const short8 pa0 = *(const short8*)&Pl[l15 * 72 + quad * 8];
            const short8 pa1 = *(const short8*)&Pl[l15 * 72 + 32 + quad * 8];
            __builtin_amdgcn_s_setprio(1);
#pragma unroll
            for (int ni = 0; ni < 4; ni++) {
                accO[tt][ni] = MFMA16(pa0, vreg[ni][0], accO[tt][ni]);
                accO[tt][ni] = MFMA16(pa1, vreg[ni][1], accO[tt][ni]);
            }
            accO[tt][4] = MFMA16(pa0, vone, accO[tt][4]);
            accO[tt][4] = MFMA16(pa1, vone, accO[tt][4]);
            __builtin_amdgcn_s_setprio(0);
        }
    }

    // Epilogue: bf16 in-place into QO at (bh, l, d) — rows this wave owns.
#pragma unroll
    for (int tt = 0; tt < 4; tt++) {
#pragma unroll
        for (int r = 0; r < 4; r++) {
            const float inv = 1.0f / fmaxf(accO[tt][4][r], 1e-30f);
            const int l = qbase + tt * 16 + quad * 4 + r;
#pragma unroll
            for (int ni = 0; ni < 4; ni++) {
                Qb[(size_t)l * 64 + ni * 16 + l15] =
                    f2bf(accO[tt][ni][r] * inv);
            }
        }
    }
}

// ---------------------------------------------------------------------------
extern "C" void kernel_launch(void* const* d_in, const int* in_sizes, int n_in,
                              void* d_out, int out_size, void* d_ws, size_t ws_size,
                              hipStream_t stream)
{
    const float* x    = (const float*)d_in[0];
    const int*   mask = (const int*)d_in[1];
    const float* wq   = (const float*)d_in[2];
    const float* bq   = (const float*)d_in[3];
    const float* wk   = (const float*)d_in[4];
    const float* bk   = (const float*)d_in[5];
    const float* wv   = (const float*)d_in[6];
    const float* bv   = (const float*)d_in[7];
    const float* wo   = (const float*)d_in[8];
    const float* bo   = (const float*)d_in[9];
    float* out = (float*)d_out;   // fp32 output (8M floats)

    // ws (48 MiB): [Qbuf bf16 16MB][Kbuf bf16 16MB][Vt bf16 16MB]
    short* Qbuf = (short*)d_ws;
    short* Kbuf = Qbuf + (size_t)8 * 1024 * 1024;
    short* Vt   = Kbuf + (size_t)8 * 1024 * 1024;

    // d_out doubles as scratch until the final GEMM writes it.
    short* Xb  = (short*)d_out;
    short* Wqb = Xb  + (size_t)8 * 1024 * 1024;
    short* Wkb = Wqb + (size_t)1024 * 1024;
    short* Wvb = Wkb + (size_t)1024 * 1024;

    dim3 block(256);

    cvt_kernel<<<dim3(4096), block, 0, stream>>>(x, Xb, 1024 * 1024);
    cvt3_kernel<<<dim3(1536), block, 0, stream>>>(wq, wk, wv, Wqb, Wkb, Wvb);

    qkv_kernel<<<dim3(64, 24), block, 0, stream>>>(
        Xb, Wqb, Wkb, Wvb, bq, bk, bv, Qbuf, Kbuf, Vt);

    // attn reads Q/K/V, writes bf16 attn-out in-place into Qbuf.
    attn_kernel<<<dim3(512), block, 0, stream>>>(Qbuf, Kbuf, Vt, mask);

    // wo -> bf16 into Kbuf (dead after attn).
    short* Wob = Kbuf;
    cvt_kernel<<<dim3(512), block, 0, stream>>>(wo, Wob, 128 * 1024);

    // Final projection: A = Qbuf in (B,H,L,dh) bf16 (layout 4), out fp32.
    gemm_kernel<<<dim3(64, 8), block, 0, stream>>>(Qbuf, Wob, bo, out, 4);
}

// Round 13
// 338.063 us; speedup vs baseline: 2.1088x; 1.0340x over previous
//
#include <hip/hip_runtime.h>

// ---------------------------------------------------------------------------
// MultiHeadSelfAttention: B=4, L=2048, D=1024, H=16, dh=64.
// R20 = R19 + vectorized layout-2 (V^T) epilogue: the 4 r-values of each
// acc[mi][ni] are 4 consecutive l positions -> one 8B short4 store instead
// of 4 scalar 2B stores at 4KB lane stride (4x fewer write transactions on
// the V panel). Values bit-identical. Everything else byte-identical to R19
// (attn in-place bf16 out, layout-4 final GEMM, no fp32 round-trip).
// ---------------------------------------------------------------------------

typedef __attribute__((ext_vector_type(8))) short short8;   // 8 bf16 = 4 VGPR
typedef __attribute__((ext_vector_type(4))) short short4v;  // 4 bf16 = 8 B
typedef __attribute__((ext_vector_type(4))) float f32x4;
typedef __attribute__((ext_vector_type(4))) float floatx4;
typedef __attribute__((ext_vector_type(4))) int int4v;
typedef __attribute__((ext_vector_type(2))) unsigned int u32x2;

#define MFMA16(a, b, c) __builtin_amdgcn_mfma_f32_16x16x32_bf16((a), (b), (c), 0, 0, 0)

__device__ __forceinline__ short f2bf(float f) {
    unsigned u = __float_as_uint(f);
    u += 0x7FFF + ((u >> 16) & 1);   // round-to-nearest-even
    return (short)(u >> 16);
}

__device__ __forceinline__ float fast_exp2(float x) {
#if __has_builtin(__builtin_amdgcn_exp2f)
    return __builtin_amdgcn_exp2f(x);   // single v_exp_f32
#else
    return exp2f(x);
#endif
}

// async global -> LDS, 16 B per lane (global_load_lds_dwordx4).
__device__ __forceinline__ void gload_lds16(const short* g, short* l) {
    __builtin_amdgcn_global_load_lds(
        (const __attribute__((address_space(1))) void*)g,
        (__attribute__((address_space(3))) void*)l, 16, 0, 0);
}

// ---------------------------------------------------------------------------
// fp32 -> bf16 bulk converts.
// ---------------------------------------------------------------------------
__device__ __forceinline__ void cvt8(const float* __restrict__ src,
                                     short* __restrict__ dst, int i) {
    const f32x4* p = (const f32x4*)src + (size_t)i * 2;
    const f32x4 u0 = p[0];
    const f32x4 u1 = p[1];
    short8 s;
    s[0] = f2bf(u0[0]); s[1] = f2bf(u0[1]); s[2] = f2bf(u0[2]); s[3] = f2bf(u0[3]);
    s[4] = f2bf(u1[0]); s[5] = f2bf(u1[1]); s[6] = f2bf(u1[2]); s[7] = f2bf(u1[3]);
    ((short8*)dst)[i] = s;
}

__global__ __launch_bounds__(256) void cvt_kernel(
    const float* __restrict__ src, short* __restrict__ dst, int n8)
{
    const int i = blockIdx.x * 256 + threadIdx.x;
    if (i >= n8) return;
    cvt8(src, dst, i);
}

// three 1024x1024 weight matrices in one launch; grid 3*512, exact.
__global__ __launch_bounds__(256) void cvt3_kernel(
    const float* __restrict__ s0, const float* __restrict__ s1,
    const float* __restrict__ s2, short* __restrict__ d0,
    short* __restrict__ d1, short* __restrict__ d2)
{
    const int which = blockIdx.x >> 9;
    const int i = (blockIdx.x & 511) * 256 + threadIdx.x;
    const float* s = which == 0 ? s0 : which == 1 ? s1 : s2;
    short* d = which == 0 ? d0 : which == 1 ? d1 : d2;
    cvt8(s, d, i);
}

// ---------------------------------------------------------------------------
// GEMM body (m97 structure): out = A(8192 x 1024) * W^T + bias, bf16 in.
// 128x128 block tile, 4 waves each 64x64, BK=32. Staging via
// global_load_lds width 16 into linear LDS [128][32]. 2 barriers per K-step.
// layout 0/1 -> out bf16 (B,H,L,dh); 2 -> out bf16 (B,H,dh,L) with
// vectorized short4 stores (4 consecutive l per thread);
// 3 -> out fp32 (M,1024); 4 -> out fp32 (M,1024) with A read from
// (B,H,L,dh) bf16: A(m,k) at b*2097152 + (k>>6)*131072 + l*64 + (k&63).
// oscale multiplies (acc+bias) before store.
// ---------------------------------------------------------------------------
__device__ __forceinline__ void gemm_body(
    const short* __restrict__ A, const short* __restrict__ W,
    const float* __restrict__ bias, void* __restrict__ out,
    int layout, int m0, int n0, float oscale)
{
    __shared__ short As[128 * 32];
    __shared__ short Bs[128 * 32];

    const int t = threadIdx.x;
    const int wave = t >> 6, lane = t & 63;
    const int wm = (wave >> 1) * 64, wn = (wave & 1) * 64;
    const int l15 = lane & 15, quad = lane >> 4;

    const int r4 = lane >> 2;           // 0..15
    const int kc = (lane & 3) * 8;      // 0,8,16,24

    short* lA0 = &As[wave * 512 + lane * 8];
    short* lA1 = &As[2048 + wave * 512 + lane * 8];
    short* lB0 = &Bs[wave * 512 + lane * 8];
    short* lB1 = &Bs[2048 + wave * 512 + lane * 8];

    const short* gA0;
    const short* gA1;
    if (layout == 4) {
        const int mA = m0 + wave * 16 + r4;
        const int bb = mA >> 11, ll = mA & 2047;
        gA0 = A + (size_t)bb * 2097152 + (size_t)ll * 64 + kc;
        gA1 = gA0 + 64 * 64;   // row +64 -> l +64 (same b within a tile)
    } else {
        gA0 = A + (size_t)(m0 + wave * 16 + r4) * 1024 + kc;
        gA1 = gA0 + (size_t)64 * 1024;
    }
    const short* gB0 = W + (size_t)(n0 + wave * 16 + r4) * 1024 + kc;
    const short* gB1 = gB0 + (size_t)64 * 1024;

    floatx4 acc[4][4];
#pragma unroll
    for (int i = 0; i < 4; i++)
#pragma unroll
        for (int j = 0; j < 4; j++) {
            acc[i][j][0] = 0.f; acc[i][j][1] = 0.f;
            acc[i][j][2] = 0.f; acc[i][j][3] = 0.f;
        }

    for (int kb = 0; kb < 1024; kb += 32) {
        const size_t aoff = (layout == 4)
            ? ((size_t)(kb >> 6) * 131072 + (size_t)(kb & 63))
            : (size_t)kb;
        gload_lds16(gA0 + aoff, lA0);
        gload_lds16(gA1 + aoff, lA1);
        gload_lds16(gB0 + kb, lB0);
        gload_lds16(gB1 + kb, lB1);
        __syncthreads();   // vmcnt(0) drain + barrier: LDS tile ready

        short8 af[4], bfr[4];
#pragma unroll
        for (int mi = 0; mi < 4; mi++)
            af[mi] = *(short8*)&As[(wm + mi * 16 + l15) * 32 + quad * 8];
#pragma unroll
        for (int ni = 0; ni < 4; ni++)
            bfr[ni] = *(short8*)&Bs[(wn + ni * 16 + l15) * 32 + quad * 8];
#pragma unroll
        for (int mi = 0; mi < 4; mi++)
#pragma unroll
            for (int ni = 0; ni < 4; ni++)
                acc[mi][ni] = MFMA16(af[mi], bfr[ni], acc[mi][ni]);

        __syncthreads();   // protect LDS from next K-step's staging
    }

    // Epilogue. C layout: col = lane&15, row = quad*4 + r.
#pragma unroll
    for (int ni = 0; ni < 4; ni++) {
        const int gn = n0 + wn + ni * 16 + l15;
        const float bv = bias[gn];
#pragma unroll
        for (int mi = 0; mi < 4; mi++) {
            if (layout == 2) {
                // 4 r-values = 4 consecutive l -> one 8B store.
                const int gm0 = m0 + wm + mi * 16 + quad * 4;
                const int b = gm0 >> 11, l0 = gm0 & 2047;
                const int h = gn >> 6,  d = gn & 63;
                short4v s4;
#pragma unroll
                for (int r = 0; r < 4; r++)
                    s4[r] = f2bf((acc[mi][ni][r] + bv) * oscale);
                *(short4v*)&((short*)out)[
                    ((size_t)((b * 16 + h) * 64 + d)) * 2048 + l0] = s4;
            } else {
#pragma unroll
                for (int r = 0; r < 4; r++) {
                    const int gm = m0 + wm + mi * 16 + quad * 4 + r;
                    const float v = (acc[mi][ni][r] + bv) * oscale;
                    if (layout >= 3) {
                        ((float*)out)[(size_t)gm * 1024 + gn] = v;
                    } else {
                        const int b = gm >> 11, l = gm & 2047;  // L = 2048
                        const int h = gn >> 6,  d = gn & 63;    // dh = 64
                        const size_t idx =
                            ((size_t)(b * 16 + h) * 2048 + l) * 64 + d;
                        ((short*)out)[idx] = f2bf(v);
                    }
                }
            }
        }
    }
}

// fused QKV: grid (64, 24); blockIdx.y>>3 selects {Q,K,V} panel.
// Q panel is pre-scaled by SC = 0.125 * log2(e) (softmax scale folded in).
__global__ __launch_bounds__(256, 3) void qkv_kernel(
    const short* __restrict__ Xb,
    const short* __restrict__ Wq, const short* __restrict__ Wk,
    const short* __restrict__ Wv,
    const float* __restrict__ bq, const float* __restrict__ bk,
    const float* __restrict__ bv,
    short* __restrict__ Qo, short* __restrict__ Ko, short* __restrict__ Vo)
{
    const int chunk = blockIdx.y >> 3;            // 0=Q,1=K,2=V
    const int n0 = (blockIdx.y & 7) * 128;
    const short* W = chunk == 0 ? Wq : chunk == 1 ? Wk : Wv;
    const float* bs = chunk == 0 ? bq : chunk == 1 ? bk : bv;
    void* out = chunk == 0 ? (void*)Qo : chunk == 1 ? (void*)Ko : (void*)Vo;
    const float os = chunk == 0 ? 0.125f * 1.44269504f : 1.0f;
    gemm_body(Xb, W, bs, out, chunk, blockIdx.x * 128, n0, os);
}

__global__ __launch_bounds__(256, 3) void gemm_kernel(
    const short* __restrict__ A, const short* __restrict__ W,
    const float* __restrict__ bias, void* __restrict__ out, int layout)
{
    gemm_body(A, W, bias, out, layout, blockIdx.x * 128, blockIdx.y * 128, 1.0f);
}

// ---------------------------------------------------------------------------
// Attention (compute loop identical to the proven R13 kernel). Q arrives
// pre-scaled by SC, so P = exp2(S + maskbias) directly. 512 blocks x 4
// waves; each wave owns 4 q-tiles (64 rows). Swapped QK^T (mfma(K,Q)); P^T
// packed via v_cvt_pk_bf16_f32 -> ds_write_b64; mask as -1e9 accumulator
// seed; row sums via ones-column MFMA. XCD-affine: bh = blk & 63.
// Epilogue (R19): bf16 in-place into QO ((B,H,L,dh)); each wave writes
// exactly the rows whose Q it loaded in its own prologue; no other block
// reads those rows -> no inter-block hazard.
// QO bf16 in/out (B,H,L,dh); K bf16 (B,H,L,dh); VT bf16 (B,H,dh,L);
// mask int32.
// ---------------------------------------------------------------------------
__global__ __launch_bounds__(256, 2) void attn_kernel(
    short* QO, const short* __restrict__ Kc,
    const short* __restrict__ VT, const int* __restrict__ mask)
{
    __shared__ short Plds_all[4][4][16 * 72];   // 36864 B

    const int blk = blockIdx.x;          // 512 blocks
    const int bh = blk & 63;             // same bh -> same XCD
    const int qg = blk >> 6;             // 0..7 (256 rows each)
    const int b = bh >> 4;
    const int t = threadIdx.x;
    const int wave = t >> 6, lane = t & 63;
    const int l15 = lane & 15, quad = lane >> 4;

    short* Qb = QO + (size_t)bh * 2048 * 64;
    const short* Kb = Kc + (size_t)bh * 2048 * 64;
    const short* Vb = VT + (size_t)bh * 64 * 2048;
    const int* mrow = mask + b * 2048;

    const int qbase = qg * 256 + wave * 64;

    short8 aq[4][2];
#pragma unroll
    for (int tt = 0; tt < 4; tt++) {
        const short* qp = Qb + (size_t)(qbase + tt * 16 + l15) * 64 + quad * 8;
        aq[tt][0] = *(const short8*)(qp);
        aq[tt][1] = *(const short8*)(qp + 32);
    }

    short8 vone;
#pragma unroll
    for (int j = 0; j < 8; j++) vone[j] = (short)0x3F80;

    floatx4 accO[4][5];
#pragma unroll
    for (int tt = 0; tt < 4; tt++)
#pragma unroll
        for (int ni = 0; ni < 5; ni++) {
            accO[tt][ni][0] = 0.f; accO[tt][ni][1] = 0.f;
            accO[tt][ni][2] = 0.f; accO[tt][ni][3] = 0.f;
        }

    for (int c0 = 0; c0 < 2048; c0 += 64) {
        short8 kreg[4][2];
#pragma unroll
        for (int g = 0; g < 4; g++) {
            const short* kp = Kb + (size_t)(c0 + g * 16 + l15) * 64 + quad * 8;
            kreg[g][0] = *(const short8*)(kp);
            kreg[g][1] = *(const short8*)(kp + 32);
        }
        f32x4 bias[4];
#pragma unroll
        for (int g = 0; g < 4; g++) {
            const int4v mv = *(const int4v*)&mrow[c0 + g * 16 + quad * 4];
#pragma unroll
            for (int r = 0; r < 4; r++) bias[g][r] = mv[r] ? -1e9f : 0.f;
        }
        short8 vreg[4][2];
#pragma unroll
        for (int ni = 0; ni < 4; ni++) {
            const short* vp = Vb + (size_t)(ni * 16 + l15) * 2048 + c0 + quad * 8;
            vreg[ni][0] = *(const short8*)(vp);
            vreg[ni][1] = *(const short8*)(vp + 32);
        }

#pragma unroll
        for (int tt = 0; tt < 4; tt++) {
            floatx4 s[4];
            __builtin_amdgcn_s_setprio(1);
#pragma unroll
            for (int g = 0; g < 4; g++) {
                floatx4 z = bias[g];
                z = MFMA16(kreg[g][0], aq[tt][0], z);
                s[g] = MFMA16(kreg[g][1], aq[tt][1], z);
            }
            __builtin_amdgcn_s_setprio(0);
            short* Pl = &Plds_all[wave][tt][0];
#pragma unroll
            for (int g = 0; g < 4; g++) {
                const float p0 = fast_exp2(s[g][0]);
                const float p1 = fast_exp2(s[g][1]);
                const float p2 = fast_exp2(s[g][2]);
                const float p3 = fast_exp2(s[g][3]);
                unsigned lo, hi;
                asm("v_cvt_pk_bf16_f32 %0, %1, %2" : "=v"(lo) : "v"(p0), "v"(p1));
                asm("v_cvt_pk_bf16_f32 %0, %1, %2" : "=v"(hi) : "v"(p2), "v"(p3));
                u32x2 w; w[0] = lo; w[1] = hi;
                *(u32x2*)&Pl[l15 * 72 + g * 16 + quad * 4] = w;
            }
        }

        asm volatile("s_waitcnt lgkmcnt(0)" ::: "memory");

#pragma unroll
        for (int tt = 0; tt < 4; tt++) {
            const short* Pl = &Plds_all[wave][tt][0];
            const short8 pa0 = *(const short8*)&Pl[l15 * 72 + quad * 8];
            const short8 pa1 = *(const short8*)&Pl[l15 * 72 + 32 + quad * 8];
            __builtin_amdgcn_s_setprio(1);
#pragma unroll
            for (int ni = 0; ni < 4; ni++) {
                accO[tt][ni] = MFMA16(pa0, vreg[ni][0], accO[tt][ni]);
                accO[tt][ni] = MFMA16(pa1, vreg[ni][1], accO[tt][ni]);
            }
            accO[tt][4] = MFMA16(pa0, vone, accO[tt][4]);
            accO[tt][4] = MFMA16(pa1, vone, accO[tt][4]);
            __builtin_amdgcn_s_setprio(0);
        }
    }

    // Epilogue: bf16 in-place into QO at (bh, l, d) — rows this wave owns.
#pragma unroll
    for (int tt = 0; tt < 4; tt++) {
#pragma unroll
        for (int r = 0; r < 4; r++) {
            const float inv = 1.0f / fmaxf(accO[tt][4][r], 1e-30f);
            const int l = qbase + tt * 16 + quad * 4 + r;
#pragma unroll
            for (int ni = 0; ni < 4; ni++) {
                Qb[(size_t)l * 64 + ni * 16 + l15] =
                    f2bf(accO[tt][ni][r] * inv);
            }
        }
    }
}

// ---------------------------------------------------------------------------
extern "C" void kernel_launch(void* const* d_in, const int* in_sizes, int n_in,
                              void* d_out, int out_size, void* d_ws, size_t ws_size,
                              hipStream_t stream)
{
    const float* x    = (const float*)d_in[0];
    const int*   mask = (const int*)d_in[1];
    const float* wq   = (const float*)d_in[2];
    const float* bq   = (const float*)d_in[3];
    const float* wk   = (const float*)d_in[4];
    const float* bk   = (const float*)d_in[5];
    const float* wv   = (const float*)d_in[6];
    const float* bv   = (const float*)d_in[7];
    const float* wo   = (const float*)d_in[8];
    const float* bo   = (const float*)d_in[9];
    float* out = (float*)d_out;   // fp32 output (8M floats)

    // ws (48 MiB): [Qbuf bf16 16MB][Kbuf bf16 16MB][Vt bf16 16MB]
    short* Qbuf = (short*)d_ws;
    short* Kbuf = Qbuf + (size_t)8 * 1024 * 1024;
    short* Vt   = Kbuf + (size_t)8 * 1024 * 1024;

    // d_out doubles as scratch until the final GEMM writes it.
    short* Xb  = (short*)d_out;
    short* Wqb = Xb  + (size_t)8 * 1024 * 1024;
    short* Wkb = Wqb + (size_t)1024 * 1024;
    short* Wvb = Wkb + (size_t)1024 * 1024;

    dim3 block(256);

    cvt_kernel<<<dim3(4096), block, 0, stream>>>(x, Xb, 1024 * 1024);
    cvt3_kernel<<<dim3(1536), block, 0, stream>>>(wq, wk, wv, Wqb, Wkb, Wvb);

    qkv_kernel<<<dim3(64, 24), block, 0, stream>>>(
        Xb, Wqb, Wkb, Wvb, bq, bk, bv, Qbuf, Kbuf, Vt);

    // attn reads Q/K/V, writes bf16 attn-out in-place into Qbuf.
    attn_kernel<<<dim3(512), block, 0, stream>>>(Qbuf, Kbuf, Vt, mask);

    // wo -> bf16 into Kbuf (dead after attn).
    short* Wob = Kbuf;
    cvt_kernel<<<dim3(512), block, 0, stream>>>(wo, Wob, 128 * 1024);

    // Final projection: A = Qbuf in (B,H,L,dh) bf16 (layout 4), out fp32.
    gemm_kernel<<<dim3(64, 8), block, 0, stream>>>(Qbuf, Wob, bo, out, 4);
}